// Round 10
// baseline (291.327 us; speedup 1.0000x reference)
//
#include <hip/hip_runtime.h>

#define LN_EPS 1e-5f
#define CA 2048          // edges per block in radix pass
#define CAPB 6144        // per-bucket LDS record capacity (bucket ~ Poisson(4096))

typedef __attribute__((ext_vector_type(8))) short short8;
typedef __attribute__((ext_vector_type(4))) float float4a;
typedef __attribute__((ext_vector_type(2))) float float2a;

__device__ __forceinline__ float lrelu(float v) { return v > 0.f ? v : 0.2f * v; }

__device__ __forceinline__ unsigned short f2bf(float f) {
    union { float f; unsigned int u; } x; x.f = f;
    unsigned int u = x.u;
    unsigned int r = (u + 0x7fffu + ((u >> 16) & 1u)) >> 16;   // RNE
    return (unsigned short)r;
}
__device__ __forceinline__ float bflo(unsigned int v) {
    union { unsigned int u; float f; } x; x.u = v << 16; return x.f;
}
__device__ __forceinline__ float bfhi(unsigned int v) {
    union { unsigned int u; float f; } x; x.u = v & 0xffff0000u; return x.f;
}
// unpack dword of 2 bf16 -> packed float2 (feeds v_pk_fma_f32)
__device__ __forceinline__ float2a bf2(unsigned int w) {
    union { unsigned int u; float f; } lo, hi;
    lo.u = w << 16; hi.u = w & 0xffff0000u;
    float2a r; r[0] = lo.f; r[1] = hi.f; return r;
}

__device__ __forceinline__ void load_lds16(const void* g, void* l) {
    __builtin_amdgcn_global_load_lds(
        (const __attribute__((address_space(1))) void*)g,
        (__attribute__((address_space(3))) void*)l, 16, 0, 0);
}

// 16B load from uniform base + 32-bit byte offset
__device__ __forceinline__ uint4 ld16(const char* __restrict__ b, unsigned off) {
    return *(const uint4*)(b + off);
}

// unmasked bf16 dual-accumulate: aw += w*f, ap += f
__device__ __forceinline__ void accb(float2a aw2[4], float2a ap2[4], float w, uint4 v) {
    float2a wm2; wm2[0] = w; wm2[1] = w;
    float2a f0 = bf2(v.x), f1 = bf2(v.y), f2v = bf2(v.z), f3 = bf2(v.w);
    aw2[0] += wm2 * f0; aw2[1] += wm2 * f1;
    aw2[2] += wm2 * f2v; aw2[3] += wm2 * f3;
    ap2[0] += f0; ap2[1] += f1;
    ap2[2] += f2v; ap2[3] += f3;
}

// masked bf16 dual-accumulate
__device__ __forceinline__ void accbm(float2a aw2[4], float2a ap2[4], float wm, float sm, uint4 v) {
    float2a wm2; wm2[0] = wm; wm2[1] = wm;
    float2a sm2; sm2[0] = sm; sm2[1] = sm;
    float2a f0 = bf2(v.x), f1 = bf2(v.y), f2v = bf2(v.z), f3 = bf2(v.w);
    aw2[0] += wm2 * f0; aw2[1] += wm2 * f1;
    aw2[2] += wm2 * f2v; aw2[3] += wm2 * f3;
    ap2[0] += sm2 * f0; ap2[1] += sm2 * f1;
    ap2[2] += sm2 * f2v; ap2[3] += sm2 * f3;
}

// ---------------- prep: W12T (256x384), W2cT (256x512), vs/vd = W_gat@att ----------------
__global__ void prep(const float* __restrict__ W_gat, const float* __restrict__ W1l,
                     const float* __restrict__ W1r, const float* __restrict__ W2l,
                     const float* __restrict__ W2r,
                     const float* __restrict__ att_s, const float* __restrict__ att_d,
                     unsigned short* __restrict__ W12T, unsigned short* __restrict__ W2cT,
                     float* __restrict__ vs, float* __restrict__ vd)
{
    int idx = blockIdx.x * 256 + threadIdx.x;
    if (idx < 98304) {                                   // W12T[c*384+k]
        int c = idx / 384, k = idx - c * 384;
        float v = 0.f;
        if (c < 128) { if (k < 128) v = W_gat[k * 128 + c]; }
        else {
            int cc = c - 128;
            if (k >= 256)       v = W1r[(k - 256) * 128 + cc];
            else if (k >= 128)  v = W1l[(k - 128) * 128 + cc];
        }
        W12T[idx] = f2bf(v);
    } else if (idx < 229376) {                           // W2cT[c*512+k]
        int t = idx - 98304;
        int c = t >> 9, k = t & 511;
        float v = (k < 256) ? W2l[k * 256 + c] : W2r[(k - 256) * 256 + c];
        W2cT[t] = f2bf(v);
    } else if (idx < 229376 + 128) {
        int k = idx - 229376;
        float s = 0.f, d = 0.f;
        for (int c = 0; c < 128; ++c) {
            float w = W_gat[k * 128 + c];
            s += w * att_s[c]; d += w * att_d[c];
        }
        vs[k] = s; vd[k] = d;
    }
}

// ---------------- conv x -> bf16 (combo3[:,256:384]) + attention logits (wave per node) ----------------
__global__ __launch_bounds__(256) void conv_x_asad(
    const float* __restrict__ x, const float* __restrict__ vs, const float* __restrict__ vd,
    unsigned short* __restrict__ combo3, float* __restrict__ as_, float* __restrict__ ad_, int N)
{
    const int wave = threadIdx.x >> 6, lane = threadIdx.x & 63;
    const int i = blockIdx.x * 4 + wave;
    if (i >= N) return;
    float2 xv = *(const float2*)(x + (size_t)i * 128 + 2 * lane);
    float2 vsv = *(const float2*)(vs + 2 * lane);
    float2 vdv = *(const float2*)(vd + 2 * lane);
    float s = xv.x * vsv.x + xv.y * vsv.y;
    float d = xv.x * vdv.x + xv.y * vdv.y;
    #pragma unroll
    for (int off = 32; off > 0; off >>= 1) {
        s += __shfl_xor(s, off);
        d += __shfl_xor(d, off);
    }
    if (lane == 0) { as_[i] = s; ad_[i] = d; }
    unsigned pk = (unsigned)f2bf(xv.x) | ((unsigned)f2bf(xv.y) << 16);
    *(unsigned*)(combo3 + (size_t)i * 384 + 256 + 2 * lane) = pk;
}

// ---------------- CSR build via 2-level bucket sort (no global atomics) ----------------
__global__ __launch_bounds__(256) void radix_hist(
    const int* __restrict__ dst, int E, int* __restrict__ blockhist, int B)
{
    const int blk = blockIdx.x, t = threadIdx.x;
    __shared__ int hist[256];
    hist[t] = 0; __syncthreads();
    const int chunk = blk * CA, cend = min(chunk + CA, E);
    for (int j = chunk + t; j < cend; j += 256)
        atomicAdd(&hist[((unsigned)dst[j]) >> 8], 1);
    __syncthreads();
    blockhist[t * B + blk] = hist[t];       // bin-major layout
}

__global__ __launch_bounds__(256) void scan_rows(
    int* __restrict__ blockhist, int B, int* __restrict__ bintot)
{
    const int bin = blockIdx.x, t = threadIdx.x;
    __shared__ int tmp[256];
    __shared__ int carry;
    if (t == 0) carry = 0;
    __syncthreads();
    const int base = bin * B;
    for (int off0 = 0; off0 < B; off0 += 256) {
        int i = off0 + t;
        int v = (i < B) ? blockhist[base + i] : 0;
        tmp[t] = v; __syncthreads();
        for (int off = 1; off < 256; off <<= 1) {
            int a = (t >= off) ? tmp[t - off] : 0;
            __syncthreads();
            tmp[t] += a;
            __syncthreads();
        }
        int incl = tmp[t] + carry;
        if (i < B) blockhist[base + i] = incl - v;
        __syncthreads();
        if (t == 255) carry = incl;
        __syncthreads();
    }
    if (t == 0) bintot[bin] = carry;
}

__global__ __launch_bounds__(256) void scan_bins(
    const int* __restrict__ bintot, int* __restrict__ bucket_base, int E)
{
    const int t = threadIdx.x;
    __shared__ int tmp[256];
    int v = bintot[t];
    tmp[t] = v; __syncthreads();
    for (int off = 1; off < 256; off <<= 1) {
        int a = (t >= off) ? tmp[t - off] : 0;
        __syncthreads();
        tmp[t] += a;
        __syncthreads();
    }
    bucket_base[t] = tmp[t] - v;
    if (t == 255) bucket_base[256] = E;
}

__global__ __launch_bounds__(256) void radix_scatter(
    const int* __restrict__ src, const int* __restrict__ dst, int E,
    const int* __restrict__ rowscan, const int* __restrict__ bucket_base,
    int B, unsigned int* __restrict__ srt)
{
    const int blk = blockIdx.x, t = threadIdx.x;
    __shared__ int hist[256], lscan[256], lcur[256], gbase[256];
    __shared__ unsigned int recs[CA];
    hist[t] = 0; __syncthreads();
    const int chunk = blk * CA, cend = min(chunk + CA, E);
    for (int j = chunk + t; j < cend; j += 256)
        atomicAdd(&hist[((unsigned)dst[j]) >> 8], 1);
    __syncthreads();
    lscan[t] = hist[t]; __syncthreads();
    for (int off = 1; off < 256; off <<= 1) {
        int a = (t >= off) ? lscan[t - off] : 0;
        __syncthreads();
        lscan[t] += a;
        __syncthreads();
    }
    int excl = lscan[t] - hist[t];
    __syncthreads();
    lscan[t] = excl; lcur[t] = excl;
    gbase[t] = bucket_base[t] + rowscan[t * B + blk];
    __syncthreads();
    for (int j = chunk + t; j < cend; j += 256) {
        int d = dst[j];
        unsigned int r = ((unsigned)d << 16) | (unsigned)src[j];
        int p = atomicAdd(&lcur[((unsigned)d) >> 8], 1);
        recs[p] = r;
    }
    __syncthreads();
    const int cnt = cend - chunk;
    for (int k = t; k < cnt; k += 256) {
        unsigned int r = recs[k];
        int bin = r >> 24;
        srt[gbase[bin] + (k - lscan[bin])] = r;
    }
}

__global__ __launch_bounds__(256) void bucket_sort(
    const unsigned int* __restrict__ srt, const int* __restrict__ bucket_base,
    unsigned short* __restrict__ col_src, int* __restrict__ rp, int N, int E)
{
    const int b = blockIdx.x, t = threadIdx.x;
    const int beg = bucket_base[b], end = bucket_base[b + 1];
    const int cnt = end - beg;
    __shared__ int hist[256], lscan[256], lcur[256];
    __shared__ unsigned int recs[CAPB];
    __shared__ unsigned short outr[CAPB];
    hist[t] = 0; __syncthreads();
    const bool fits = cnt <= CAPB;
    if (fits) {
        for (int j = beg + t; j < end; j += 256) {
            unsigned int r = srt[j];
            recs[j - beg] = r;
            atomicAdd(&hist[(r >> 16) & 255], 1);
        }
    } else {
        for (int j = beg + t; j < end; j += 256)
            atomicAdd(&hist[(srt[j] >> 16) & 255], 1);
    }
    __syncthreads();
    lscan[t] = hist[t]; __syncthreads();
    for (int off = 1; off < 256; off <<= 1) {
        int a = (t >= off) ? lscan[t - off] : 0;
        __syncthreads();
        lscan[t] += a;
        __syncthreads();
    }
    int excl = lscan[t] - hist[t];
    __syncthreads();
    lscan[t] = excl; lcur[t] = excl;
    int d = (b << 8) + t;
    if (d < N) rp[d] = beg + excl;
    if (b == gridDim.x - 1 && t == 0) rp[N] = E;
    __syncthreads();
    if (fits) {
        for (int k = t; k < cnt; k += 256) {
            unsigned int r = recs[k];
            int p = atomicAdd(&lcur[(r >> 16) & 255], 1);
            outr[p] = (unsigned short)(r & 0xFFFFu);
        }
        __syncthreads();
        for (int k = t; k < cnt; k += 256)
            col_src[beg + k] = outr[k];
    } else {
        for (int j = beg + t; j < end; j += 256) {
            unsigned int r = srt[j];
            int p = atomicAdd(&lcur[(r >> 16) & 255], 1);
            col_src[beg + p] = (unsigned short)(r & 0xFFFFu);
        }
    }
}

// ---------------- fused GAT-weighted mean + SAGE1 mean over x (bf16 payload) ----------------
// 2 nodes per wave: lanes 0-31 = node A, 32-63 = node B; 2 groups of 16 per node.
__global__ __launch_bounds__(256) void gat_sage1(
    const int* __restrict__ row_ptr, const unsigned short* __restrict__ col_src,
    const float* __restrict__ as_, const float* __restrict__ ad_,
    unsigned short* __restrict__ combo3, int N)
{
    const int wave = threadIdx.x >> 6, lane = threadIdx.x & 63;
    const int half = lane >> 5, hl = lane & 31;
    const int g2 = (lane >> 4) & 1, l15 = lane & 15;
    const int h32 = half << 5;
    const int i = blockIdx.x * 8 + wave * 2 + half;
    const bool valid = i < N;

    const int beg = valid ? row_ptr[i] : 0;
    const int end = valid ? row_ptr[i + 1] : 0;
    const int deg = end - beg;
    const float adi = valid ? ad_[i] : 0.f;
    const float wself = valid ? __expf(lrelu(as_[i] + adi)) : 0.f;

    int j = beg + hl;
    int sn_l = (j < end) ? (int)col_src[j] : 0;
    float w_l = (j < end) ? __expf(lrelu(as_[sn_l] + adi)) : 0.f;
    int o_l = sn_l * 768;                      // pre-scaled row byte-offset

    const char* cb = (const char*)combo3;
    const unsigned lo = 512u + 16u * (unsigned)l15;   // x-part col slice within row

    uint4 sv = ld16(cb, (unsigned)(valid ? i : 0) * 768u + lo);
    const int dc = deg < 32 ? deg : 32;
    const int nr = dc >> 2;                    // full 4-edge rounds (2 per group)
    uint4 pv0, pv1; float pw0 = 0.f, pw1 = 0.f;
    if (nr > 0) {
        int so0 = __shfl(o_l, h32 + g2), so1 = __shfl(o_l, h32 + 2 + g2);
        pw0 = __shfl(w_l, h32 + g2); pw1 = __shfl(w_l, h32 + 2 + g2);
        pv0 = ld16(cb, lo + (unsigned)so0);
        pv1 = ld16(cb, lo + (unsigned)so1);
    }

    float2a aw2[4], ap2[4];
    {   // self term (weighted only; g2==0 carries it)
        float wm = (g2 == 0) ? wself : 0.f;
        float2a wm2; wm2[0] = wm; wm2[1] = wm;
        aw2[0] = wm2 * bf2(sv.x); aw2[1] = wm2 * bf2(sv.y);
        aw2[2] = wm2 * bf2(sv.z); aw2[3] = wm2 * bf2(sv.w);
        #pragma unroll
        for (int k = 0; k < 4; ++k) { ap2[k][0] = 0.f; ap2[k][1] = 0.f; }
    }

    for (int r = 0; r < nr; ++r) {             // prefetched 4-edge rounds
        uint4 cv0 = pv0, cv1 = pv1;
        float cw0 = pw0, cw1 = pw1;
        if (r + 1 < nr) {
            int b4 = (r + 1) * 4;
            int so0 = __shfl(o_l, h32 + b4 + g2), so1 = __shfl(o_l, h32 + b4 + 2 + g2);
            pw0 = __shfl(w_l, h32 + b4 + g2); pw1 = __shfl(w_l, h32 + b4 + 2 + g2);
            pv0 = ld16(cb, lo + (unsigned)so0);
            pv1 = ld16(cb, lo + (unsigned)so1);
        }
        accb(aw2, ap2, cw0, cv0);
        accb(aw2, ap2, cw1, cv1);
    }
    for (int j2 = nr * 4; j2 < dc; j2 += 2) {  // masked pair tail
        int eidx = j2 + g2;
        bool val = eidx < dc;
        int so  = __shfl(o_l, h32 + (val ? eidx : 0));
        float w = __shfl(w_l, h32 + (val ? eidx : 0));
        uint4 v = ld16(cb, lo + (unsigned)so);
        accbm(aw2, ap2, val ? w : 0.f, val ? 1.f : 0.f, v);
    }
    for (int j3 = 32; j3 < deg; ++j3) {        // rare tail (deg > 32), gather part
        int sn = col_src[beg + j3];
        float w = __expf(lrelu(as_[sn] + adi));
        uint4 v = ld16(cb, lo + (unsigned)(sn * 768));
        accbm(aw2, ap2, (g2 == 0) ? w : 0.f, (g2 == 0) ? 1.f : 0.f, v);
    }

    // denominator: per-lane partial (32 edges/half) + rare tail, then 5-level half-reduce
    float s = w_l;
    for (int jj = beg + hl + 32; jj < end; jj += 32)
        s += __expf(lrelu(as_[col_src[jj]] + adi));
    #pragma unroll
    for (int off = 16; off > 0; off >>= 1) s += __shfl_xor(s, off);
    const float denom = s + wself;

    float aw[8], ap[8];
    #pragma unroll
    for (int k = 0; k < 4; ++k) {
        aw[2 * k] = aw2[k][0]; aw[2 * k + 1] = aw2[k][1];
        ap[2 * k] = ap2[k][0]; ap[2 * k + 1] = ap2[k][1];
    }
    #pragma unroll
    for (int k = 0; k < 8; ++k) {              // single cross-group combine (within half)
        aw[k] += __shfl_xor(aw[k], 16);
        ap[k] += __shfl_xor(ap[k], 16);
    }
    if (valid && g2 == 0) {     // wx -> combo3[:,0:128]
        float inv = 1.f / denom;
        uint4 pk;
        pk.x = (unsigned)f2bf(aw[0] * inv) | ((unsigned)f2bf(aw[1] * inv) << 16);
        pk.y = (unsigned)f2bf(aw[2] * inv) | ((unsigned)f2bf(aw[3] * inv) << 16);
        pk.z = (unsigned)f2bf(aw[4] * inv) | ((unsigned)f2bf(aw[5] * inv) << 16);
        pk.w = (unsigned)f2bf(aw[6] * inv) | ((unsigned)f2bf(aw[7] * inv) << 16);
        *(uint4*)(combo3 + (size_t)i * 384 + 8 * l15) = pk;
    } else if (valid && g2 == 1) {  // agg1 -> combo3[:,128:256]
        float dinv = 1.f / fmaxf((float)deg, 1.f);
        uint4 pk;
        pk.x = (unsigned)f2bf(ap[0] * dinv) | ((unsigned)f2bf(ap[1] * dinv) << 16);
        pk.y = (unsigned)f2bf(ap[2] * dinv) | ((unsigned)f2bf(ap[3] * dinv) << 16);
        pk.z = (unsigned)f2bf(ap[4] * dinv) | ((unsigned)f2bf(ap[5] * dinv) << 16);
        pk.w = (unsigned)f2bf(ap[6] * dinv) | ((unsigned)f2bf(ap[7] * dinv) << 16);
        *(uint4*)(combo3 + (size_t)i * 384 + 128 + 8 * l15) = pk;
    }
}

// swizzled staging column for lane slot v: global kk block to fetch
__device__ __forceinline__ int swz_kk(int v) {
    return (((v & 7) ^ ((v >> 3) & 7)) * 8);
}

// ---------------- GEMM h = combo3 @ W12T^T + bias, fused LN1+ReLU -> bf16 h + fp8 hq ----------------
// BM=64, BN=256, BK=64, K=384. XOR-swizzled LDS. K-split by wave (skips W12T zero block).
__global__ __launch_bounds__(256) void gemm12_ln(
    const unsigned short* __restrict__ combo3, int M,
    const unsigned short* __restrict__ W12T,
    const float* __restrict__ b_gat, const float* __restrict__ b1l,
    const float* __restrict__ g1, const float* __restrict__ bb1,
    unsigned short* __restrict__ combo2, unsigned char* __restrict__ hq)
{
    __shared__ __align__(16) unsigned short As[64 * 64];
    __shared__ __align__(16) unsigned short Ws[256 * 64];   // staging uses first 128x64; Hs repack uses all
    const int tid = threadIdx.x;
    const int bm = blockIdx.x * 64;
    const int wave = tid >> 6, lane = tid & 63;
    const int quad = lane >> 4, l15 = lane & 15;
    const int swz_rd = (l15 & 7) * 8;          // read-side XOR

    float4a acc[4][4];
    const float4a z4 = {0.f, 0.f, 0.f, 0.f};
    #pragma unroll
    for (int i = 0; i < 4; ++i)
        #pragma unroll
        for (int j = 0; j < 4; ++j) acc[i][j] = z4;

    for (int k0 = 0; k0 < 384; k0 += 64) {
        const bool low = k0 < 128;
        const int rbase = low ? 0 : 128;       // active output-col half for this K-step
        #pragma unroll
        for (int it = 0; it < 2; ++it) {
            int v = tid + it * 256;
            int r = v >> 3, kk = swz_kk(v);
            if (bm + r < M)
                load_lds16(combo3 + (size_t)(bm + r) * 384 + k0 + kk, &As[v * 8]);
        }
        #pragma unroll
        for (int it = 0; it < 4; ++it) {       // stage only the active 128-row half of W12T
            int v = tid + it * 256;            // 0..1023: rloc 0..127
            int r = v >> 3, kk = swz_kk(v);
            load_lds16(W12T + (size_t)(rbase + r) * 384 + k0 + kk, &Ws[v * 8]);
        }
        __syncthreads();
        if ((wave < 2) == low) {               // wave active only in its K-range
            #pragma unroll
            for (int ks = 0; ks < 64; ks += 32) {
                short8 af[4], bfr[4];
                #pragma unroll
                for (int i = 0; i < 4; ++i)
                    af[i] = *(const short8*)(&As[(i * 16 + l15) * 64 + ((ks + quad * 8) ^ swz_rd)]);
                #pragma unroll
                for (int j = 0; j < 4; ++j)
                    bfr[j] = *(const short8*)(&Ws[((wave & 1) * 64 + j * 16 + l15) * 64 + ((ks + quad * 8) ^ swz_rd)]);
                #pragma unroll
                for (int i = 0; i < 4; ++i)
                    #pragma unroll
                    for (int j = 0; j < 4; ++j)
                        acc[i][j] = __builtin_amdgcn_mfma_f32_16x16x32_bf16(af[i], bfr[j], acc[i][j], 0, 0, 0);
            }
        }
        __syncthreads();
    }
    // epilogue: bias + LN + ReLU
    int col[4]; float bcol[4], gc[4], bc2[4];
    #pragma unroll
    for (int j = 0; j < 4; ++j) {
        int c = wave * 64 + j * 16 + l15;
        col[j] = c;
        bcol[j] = (c < 128) ? b_gat[c] : b1l[c - 128];
        gc[j] = g1[c]; bc2[j] = bb1[c];
    }
    float* lsum = (float*)As;         // 256 floats
    float* lsq  = lsum + 256;         // 256 floats
    #pragma unroll
    for (int i = 0; i < 4; ++i)
        #pragma unroll
        for (int r = 0; r < 4; ++r) {
            float ps = 0.f, pq = 0.f;
            #pragma unroll
            for (int j = 0; j < 4; ++j) {
                float v = acc[i][j][r] + bcol[j];
                ps += v; pq += v * v;
            }
            #pragma unroll
            for (int off = 1; off < 16; off <<= 1) {
                ps += __shfl_xor(ps, off);
                pq += __shfl_xor(pq, off);
            }
            if (l15 == 0) {
                int row = i * 16 + quad * 4 + r;
                lsum[row * 4 + wave] = ps;
                lsq[row * 4 + wave]  = pq;
            }
        }
    __syncthreads();
    unsigned short* Hs = Ws;          // 64 x 256 bf16 repack buffer
    #pragma unroll
    for (int i = 0; i < 4; ++i)
        #pragma unroll
        for (int r = 0; r < 4; ++r) {
            int row = i * 16 + quad * 4 + r;
            float su = lsum[row * 4] + lsum[row * 4 + 1] + lsum[row * 4 + 2] + lsum[row * 4 + 3];
            float sq = lsq[row * 4] + lsq[row * 4 + 1] + lsq[row * 4 + 2] + lsq[row * 4 + 3];
            float mu = su * (1.f / 256.f);
            float var = sq * (1.f / 256.f) - mu * mu;
            float rs = rsqrtf(var + LN_EPS);
            #pragma unroll
            for (int j = 0; j < 4; ++j) {
                float v = acc[i][j][r] + bcol[j];
                float o = fmaxf((v - mu) * rs * gc[j] + bc2[j], 0.f);
                Hs[row * 256 + col[j]] = f2bf(o);
            }
        }
    __syncthreads();
    #pragma unroll
    for (int it = 0; it < 8; ++it) {        // bf16 h -> combo2[:,256:512]
        int v = tid + it * 256;
        int r = v >> 5, cc = (v & 31) * 8;
        if (bm + r < M)
            *(uint4*)(combo2 + (size_t)(bm + r) * 512 + 256 + cc) = *(const uint4*)(&Hs[r * 256 + cc]);
    }
    #pragma unroll
    for (int it = 0; it < 4; ++it) {        // fp8 h -> hq (gather payload)
        int v = tid + it * 256;
        int r = v >> 4, c16 = (v & 15) * 16;
        if (bm + r < M) {
            uint4 o;
            #pragma unroll
            for (int q = 0; q < 4; ++q) {
                unsigned int w0 = *(const unsigned int*)(&Hs[r * 256 + c16 + q * 4 + 0]);
                unsigned int w1 = *(const unsigned int*)(&Hs[r * 256 + c16 + q * 4 + 2]);
                unsigned int t0 = __builtin_amdgcn_cvt_pk_fp8_f32(bflo(w0), bfhi(w0), 0, false);
                unsigned int t1 = __builtin_amdgcn_cvt_pk_fp8_f32(bflo(w1), bfhi(w1), t0, true);
                ((unsigned int*)&o)[q] = t1;
            }
            *(uint4*)(hq + (size_t)(bm + r) * 256 + c16) = o;
        }
    }
}

// ---------------- SAGE2 mean aggregate over fp8 hq (2 nodes per wave, half-split) ----------------
__global__ __launch_bounds__(256) void sage2_agg(
    const int* __restrict__ row_ptr, const unsigned short* __restrict__ col_src,
    const unsigned char* __restrict__ hq, unsigned short* __restrict__ combo2, int N)
{
    const int wave = threadIdx.x >> 6, lane = threadIdx.x & 63;
    const int half = lane >> 5, hl = lane & 31;
    const int g2 = (lane >> 4) & 1, l15 = lane & 15;
    const int h32 = half << 5;
    const int i = blockIdx.x * 8 + wave * 2 + half;
    const bool valid = i < N;

    const int beg = valid ? row_ptr[i] : 0;
    const int end = valid ? row_ptr[i + 1] : 0;
    const int deg = end - beg;
    int cidx = (beg + hl < end) ? (int)col_src[beg + hl] : 0;
    int o_l = cidx * 256;                      // pre-scaled row byte-offset
    const char* hb = (const char*)hq;
    const unsigned lo = 16u * (unsigned)l15;
    float2a a2[8];
    #pragma unroll
    for (int k = 0; k < 8; ++k) { a2[k][0] = 0.f; a2[k][1] = 0.f; }
    const int dc = deg < 32 ? deg : 32;
    int j = 0;
    for (; j + 4 <= dc; j += 4) {          // unmasked 4-edge rounds (2 per group)
        #pragma unroll
        for (int u = 0; u < 2; ++u) {
            int eidx = j + 2 * u + g2;
            int so = __shfl(o_l, h32 + eidx);
            uint4 v = ld16(hb, lo + (unsigned)so);
            a2[0] += __builtin_amdgcn_cvt_pk_f32_fp8(v.x, false);
            a2[1] += __builtin_amdgcn_cvt_pk_f32_fp8(v.x, true);
            a2[2] += __builtin_amdgcn_cvt_pk_f32_fp8(v.y, false);
            a2[3] += __builtin_amdgcn_cvt_pk_f32_fp8(v.y, true);
            a2[4] += __builtin_amdgcn_cvt_pk_f32_fp8(v.z, false);
            a2[5] += __builtin_amdgcn_cvt_pk_f32_fp8(v.z, true);
            a2[6] += __builtin_amdgcn_cvt_pk_f32_fp8(v.w, false);
            a2[7] += __builtin_amdgcn_cvt_pk_f32_fp8(v.w, true);
        }
    }
    for (; j < dc; j += 2) {               // masked pair tail
        int eidx = j + g2;
        bool val = eidx < dc;
        int so = __shfl(o_l, h32 + (val ? eidx : 0));
        uint4 v = ld16(hb, lo + (unsigned)so);
        float mlt = val ? 1.f : 0.f;
        float2a m2; m2[0] = mlt; m2[1] = mlt;
        a2[0] += m2 * __builtin_amdgcn_cvt_pk_f32_fp8(v.x, false);
        a2[1] += m2 * __builtin_amdgcn_cvt_pk_f32_fp8(v.x, true);
        a2[2] += m2 * __builtin_amdgcn_cvt_pk_f32_fp8(v.y, false);
        a2[3] += m2 * __builtin_amdgcn_cvt_pk_f32_fp8(v.y, true);
        a2[4] += m2 * __builtin_amdgcn_cvt_pk_f32_fp8(v.z, false);
        a2[5] += m2 * __builtin_amdgcn_cvt_pk_f32_fp8(v.z, true);
        a2[6] += m2 * __builtin_amdgcn_cvt_pk_f32_fp8(v.w, false);
        a2[7] += m2 * __builtin_amdgcn_cvt_pk_f32_fp8(v.w, true);
    }
    for (int j3 = 32; j3 < deg; ++j3) {    // rare tail (deg > 32)
        int sn = col_src[beg + j3];
        uint4 v = ld16(hb, lo + (unsigned)(sn * 256));
        float mlt = (g2 == 0) ? 1.f : 0.f;
        float2a m2; m2[0] = mlt; m2[1] = mlt;
        a2[0] += m2 * __builtin_amdgcn_cvt_pk_f32_fp8(v.x, false);
        a2[1] += m2 * __builtin_amdgcn_cvt_pk_f32_fp8(v.x, true);
        a2[2] += m2 * __builtin_amdgcn_cvt_pk_f32_fp8(v.y, false);
        a2[3] += m2 * __builtin_amdgcn_cvt_pk_f32_fp8(v.y, true);
        a2[4] += m2 * __builtin_amdgcn_cvt_pk_f32_fp8(v.z, false);
        a2[5] += m2 * __builtin_amdgcn_cvt_pk_f32_fp8(v.z, true);
        a2[6] += m2 * __builtin_amdgcn_cvt_pk_f32_fp8(v.w, false);
        a2[7] += m2 * __builtin_amdgcn_cvt_pk_f32_fp8(v.w, true);
    }
    float a[16];
    #pragma unroll
    for (int k = 0; k < 8; ++k) { a[2 * k] = a2[k][0]; a[2 * k + 1] = a2[k][1]; }
    #pragma unroll
    for (int k = 0; k < 16; ++k)               // single cross-group combine (within half)
        a[k] += __shfl_xor(a[k], 16);
    if (valid && g2 == 0) {
        float dinv = 1.f / fmaxf((float)deg, 1.f);
        uint4 pk0, pk1;
        pk0.x = (unsigned)f2bf(a[0] * dinv)  | ((unsigned)f2bf(a[1] * dinv)  << 16);
        pk0.y = (unsigned)f2bf(a[2] * dinv)  | ((unsigned)f2bf(a[3] * dinv)  << 16);
        pk0.z = (unsigned)f2bf(a[4] * dinv)  | ((unsigned)f2bf(a[5] * dinv)  << 16);
        pk0.w = (unsigned)f2bf(a[6] * dinv)  | ((unsigned)f2bf(a[7] * dinv)  << 16);
        pk1.x = (unsigned)f2bf(a[8] * dinv)  | ((unsigned)f2bf(a[9] * dinv)  << 16);
        pk1.y = (unsigned)f2bf(a[10] * dinv) | ((unsigned)f2bf(a[11] * dinv) << 16);
        pk1.z = (unsigned)f2bf(a[12] * dinv) | ((unsigned)f2bf(a[13] * dinv) << 16);
        pk1.w = (unsigned)f2bf(a[14] * dinv) | ((unsigned)f2bf(a[15] * dinv) << 16);
        *(uint4*)(combo2 + (size_t)i * 512 + 16 * l15)     = pk0;
        *(uint4*)(combo2 + (size_t)i * 512 + 16 * l15 + 8) = pk1;
    }
}

// ---------------- GEMM h2 = combo2 @ W2cT^T + b2l, fused LN2+ReLU+classifier -> out ----------------
// BM=128, BN=256, BK=64, K=512: doubled M-tile amortizes Ws staging; 32 MFMA/wave/barrier-pair.
__global__ __launch_bounds__(256) void gemm3_out(
    const unsigned short* __restrict__ combo2, int M,
    const unsigned short* __restrict__ W2cT,
    const float* __restrict__ b2l,
    const float* __restrict__ g2, const float* __restrict__ bb2,
    const float* __restrict__ Wc, const float* __restrict__ bc,
    float* __restrict__ out)
{
    __shared__ __align__(16) unsigned short As[128 * 64];
    __shared__ __align__(16) unsigned short Ws[256 * 64];
    const int tid = threadIdx.x;
    const int bm = blockIdx.x * 128;
    const int wave = tid >> 6, lane = tid & 63;
    const int quad = lane >> 4, l15 = lane & 15;
    const int swz_rd = (l15 & 7) * 8;

    float4a acc[8][4];
    const float4a z4 = {0.f, 0.f, 0.f, 0.f};
    #pragma unroll
    for (int i = 0; i < 8; ++i)
        #pragma unroll
        for (int j = 0; j < 4; ++j) acc[i][j] = z4;

    for (int k0 = 0; k0 < 512; k0 += 64) {
        #pragma unroll
        for (int it = 0; it < 4; ++it) {       // stage 128 rows of combo2
            int v = tid + it * 256;
            int r = v >> 3, kk = swz_kk(v);
            if (bm + r < M)
                load_lds16(combo2 + (size_t)(bm + r) * 512 + k0 + kk, &As[v * 8]);
        }
        #pragma unroll
        for (int it = 0; it < 8; ++it) {
            int v = tid + it * 256;
            int r = v >> 3, kk = swz_kk(v);
            load_lds16(W2cT + (size_t)r * 512 + k0 + kk, &Ws[v * 8]);
        }
        __syncthreads();
        #pragma unroll
        for (int ks = 0; ks < 64; ks += 32) {
            short8 af[8], bfr[4];
            #pragma unroll
            for (int i = 0; i < 8; ++i)
                af[i] = *(const short8*)(&As[(i * 16 + l15) * 64 + ((ks + quad * 8) ^ swz_rd)]);
            #pragma unroll
            for (int j = 0; j < 4; ++j)
                bfr[j] = *(const short8*)(&Ws[(wave * 64 + j * 16 + l15) * 64 + ((ks + quad * 8) ^ swz_rd)]);
            #pragma unroll
            for (int i = 0; i < 8; ++i)
                #pragma unroll
                for (int j = 0; j < 4; ++j)
                    acc[i][j] = __builtin_amdgcn_mfma_f32_16x16x32_bf16(af[i], bfr[j], acc[i][j], 0, 0, 0);
        }
        __syncthreads();
    }
    int col[4]; float bcol[4], gc[4], bc2[4], wcl[4];
    #pragma unroll
    for (int j = 0; j < 4; ++j) {
        int c = wave * 64 + j * 16 + l15;
        col[j] = c;
        bcol[j] = b2l[c];
        gc[j] = g2[c]; bc2[j] = bb2[c]; wcl[j] = Wc[c];
    }
    float* lsum = (float*)As;          // 512 floats
    float* lsq  = lsum + 512;          // 512 floats
    float* ldot = lsum + 1024;         // 512 floats
    #pragma unroll
    for (int i = 0; i < 8; ++i)
        #pragma unroll
        for (int r = 0; r < 4; ++r) {
            float ps = 0.f, pq = 0.f;
            #pragma unroll
            for (int j = 0; j < 4; ++j) {
                float v = acc[i][j][r] + bcol[j];
                ps += v; pq += v * v;
            }
            #pragma unroll
            for (int off = 1; off < 16; off <<= 1) {
                ps += __shfl_xor(ps, off);
                pq += __shfl_xor(pq, off);
            }
            if (l15 == 0) {
                int row = i * 16 + quad * 4 + r;
                lsum[row * 4 + wave] = ps;
                lsq[row * 4 + wave]  = pq;
            }
        }
    __syncthreads();
    #pragma unroll
    for (int i = 0; i < 8; ++i)
        #pragma unroll
        for (int r = 0; r < 4; ++r) {
            int row = i * 16 + quad * 4 + r;
            float su = lsum[row * 4] + lsum[row * 4 + 1] + lsum[row * 4 + 2] + lsum[row * 4 + 3];
            float sq = lsq[row * 4] + lsq[row * 4 + 1] + lsq[row * 4 + 2] + lsq[row * 4 + 3];
            float mu = su * (1.f / 256.f);
            float var = sq * (1.f / 256.f) - mu * mu;
            float rs = rsqrtf(var + LN_EPS);
            float pd = 0.f;
            #pragma unroll
            for (int j = 0; j < 4; ++j) {
                float v = acc[i][j][r] + bcol[j];
                float o = fmaxf((v - mu) * rs * gc[j] + bc2[j], 0.f);
                pd += o * wcl[j];
            }
            #pragma unroll
            for (int off = 1; off < 16; off <<= 1) pd += __shfl_xor(pd, off);
            if (l15 == 0) ldot[row * 4 + wave] = pd;
        }
    __syncthreads();
    if (tid < 128 && bm + tid < M)
        out[bm + tid] = ldot[tid * 4] + ldot[tid * 4 + 1] + ldot[tid * 4 + 2] + ldot[tid * 4 + 3] + bc[0];
}

extern "C" void kernel_launch(void* const* d_in, const int* in_sizes, int n_in,
                              void* d_out, int out_size, void* d_ws, size_t ws_size,
                              hipStream_t stream)
{
    const float* x     = (const float*)d_in[0];
    const int*   ei    = (const int*)d_in[1];
    const float* W_gat = (const float*)d_in[2];
    const float* att_s = (const float*)d_in[3];
    const float* att_d = (const float*)d_in[4];
    const float* b_gat = (const float*)d_in[5];
    const float* W1l   = (const float*)d_in[6];
    const float* b1l   = (const float*)d_in[7];
    const float* W1r   = (const float*)d_in[8];
    const float* ln1g  = (const float*)d_in[9];
    const float* ln1b  = (const float*)d_in[10];
    const float* W2l   = (const float*)d_in[11];
    const float* b2l   = (const float*)d_in[12];
    const float* W2r   = (const float*)d_in[13];
    const float* ln2g  = (const float*)d_in[14];
    const float* ln2b  = (const float*)d_in[15];
    const float* Wc    = (const float*)d_in[16];
    const float* bc    = (const float*)d_in[17];

    const int N = in_sizes[0] / 128;
    const int E = in_sizes[1] / 2;
    const int* srcp = ei;
    const int* dstp = ei + E;

    char* p = (char*)d_ws;
    unsigned short* combo3 = (unsigned short*)p; p += (size_t)N * 384 * 2;  // [wx | agg1 | x_bf]
    unsigned short* combo2 = (unsigned short*)p; p += (size_t)N * 512 * 2;  // [agg2 | h_ln]
    unsigned char* hq     = (unsigned char*)p;  p += (size_t)N * 256;       // fp8 h (gather payload)
    float* as_    = (float*)p;                 p += (size_t)N * 4;
    float* ad_    = (float*)p;                 p += (size_t)N * 4;
    float* vs     = (float*)p;                 p += 128 * 4;
    float* vd     = (float*)p;                 p += 128 * 4;
    unsigned short* W12T = (unsigned short*)p; p += (size_t)256 * 384 * 2;
    unsigned short* W2cT = (unsigned short*)p; p += (size_t)256 * 512 * 2;
    unsigned int* srt    = (unsigned int*)p;   p += (size_t)E * 4;
    unsigned short* col_src = (unsigned short*)p; p += (((size_t)E * 2 + 15) & ~15ull);
    int* rp       = (int*)p;                   p += (size_t)(N + 1) * 4;
    const int B   = (E + CA - 1) / CA;         // radix blocks
    int* blockhist = (int*)p;                  p += (size_t)256 * B * 4;
    int* bucket_base = (int*)p;                p += 257 * 4;
    int* bintot   = (int*)p;                   p += 256 * 4;

    dim3 b256(256);
    const int mb64 = (N + 63) / 64;
    const int mb128 = (N + 127) / 128;
    const int nb = (N + 255) >> 8;             // coarse buckets
    const int prep_total = 229376 + 128;

    // --- prep + x conversion/logits ---
    hipLaunchKernelGGL(prep, dim3((prep_total + 255) / 256), b256, 0, stream,
                       W_gat, W1l, W1r, W2l, W2r, att_s, att_d, W12T, W2cT, vs, vd);
    hipLaunchKernelGGL(conv_x_asad, dim3((N + 3) / 4), b256, 0, stream,
                       x, vs, vd, combo3, as_, ad_, N);

    // --- CSR by dst: bucket sort (no global atomics; 2-level parallel scan) ---
    hipLaunchKernelGGL(radix_hist, dim3(B), b256, 0, stream, dstp, E, blockhist, B);
    hipLaunchKernelGGL(scan_rows, dim3(256), b256, 0, stream, blockhist, B, bintot);
    hipLaunchKernelGGL(scan_bins, dim3(1), b256, 0, stream, bintot, bucket_base, E);
    hipLaunchKernelGGL(radix_scatter, dim3(B), b256, 0, stream,
                       srcp, dstp, E, blockhist, bucket_base, B, srt);
    hipLaunchKernelGGL(bucket_sort, dim3(nb), b256, 0, stream,
                       srt, bucket_base, col_src, rp, N, E);

    // --- GAT wmean + SAGE1 mean over x (2 nodes/wave half-split) ---
    hipLaunchKernelGGL(gat_sage1, dim3((N + 7) / 8), b256, 0, stream,
                       rp, col_src, as_, ad_, combo3, N);

    // --- h = combo3 @ W12T^T + bias, LN1+ReLU fused -> combo2[:,256:512] bf16 + hq fp8 ---
    hipLaunchKernelGGL(gemm12_ln, dim3(mb64), b256, 0, stream,
                       combo3, N, W12T, b_gat, b1l, ln1g, ln1b, combo2, hq);

    // --- SAGE2 aggregate (fp8 gather, 2 nodes/wave half-split) -> combo2[:,0:256] ---
    hipLaunchKernelGGL(sage2_agg, dim3((N + 7) / 8), b256, 0, stream,
                       rp, col_src, hq, combo2, N);

    // --- h2 GEMM (BM=128) + LN2 + ReLU + classifier -> out ---
    hipLaunchKernelGGL(gemm3_out, dim3(mb128), b256, 0, stream,
                       combo2, N, W2cT, b2l, ln2g, ln2b, Wc, bc, (float*)d_out);
}

// Round 11
// 283.507 us; speedup vs baseline: 1.0276x; 1.0276x over previous
//
#include <hip/hip_runtime.h>

#define LN_EPS 1e-5f
#define CA 2048          // edges per block in radix pass
#define CAPB 6144        // per-bucket LDS record capacity (bucket ~ Poisson(4096))

typedef __attribute__((ext_vector_type(8))) short short8;
typedef __attribute__((ext_vector_type(4))) float float4a;
typedef __attribute__((ext_vector_type(2))) float float2a;

__device__ __forceinline__ float lrelu(float v) { return v > 0.f ? v : 0.2f * v; }

__device__ __forceinline__ unsigned short f2bf(float f) {
    union { float f; unsigned int u; } x; x.f = f;
    unsigned int u = x.u;
    unsigned int r = (u + 0x7fffu + ((u >> 16) & 1u)) >> 16;   // RNE
    return (unsigned short)r;
}
__device__ __forceinline__ float bflo(unsigned int v) {
    union { unsigned int u; float f; } x; x.u = v << 16; return x.f;
}
__device__ __forceinline__ float bfhi(unsigned int v) {
    union { unsigned int u; float f; } x; x.u = v & 0xffff0000u; return x.f;
}
// unpack dword of 2 bf16 -> packed float2 (feeds v_pk_fma_f32)
__device__ __forceinline__ float2a bf2(unsigned int w) {
    union { unsigned int u; float f; } lo, hi;
    lo.u = w << 16; hi.u = w & 0xffff0000u;
    float2a r; r[0] = lo.f; r[1] = hi.f; return r;
}

__device__ __forceinline__ void load_lds16(const void* g, void* l) {
    __builtin_amdgcn_global_load_lds(
        (const __attribute__((address_space(1))) void*)g,
        (__attribute__((address_space(3))) void*)l, 16, 0, 0);
}

// 16B load from uniform base + 32-bit byte offset
__device__ __forceinline__ uint4 ld16(const char* __restrict__ b, unsigned off) {
    return *(const uint4*)(b + off);
}

// unmasked bf16 dual-accumulate: aw += w*f, ap += f
__device__ __forceinline__ void accb(float2a aw2[4], float2a ap2[4], float w, uint4 v) {
    float2a wm2; wm2[0] = w; wm2[1] = w;
    float2a f0 = bf2(v.x), f1 = bf2(v.y), f2v = bf2(v.z), f3 = bf2(v.w);
    aw2[0] += wm2 * f0; aw2[1] += wm2 * f1;
    aw2[2] += wm2 * f2v; aw2[3] += wm2 * f3;
    ap2[0] += f0; ap2[1] += f1;
    ap2[2] += f2v; ap2[3] += f3;
}

// masked bf16 dual-accumulate
__device__ __forceinline__ void accbm(float2a aw2[4], float2a ap2[4], float wm, float sm, uint4 v) {
    float2a wm2; wm2[0] = wm; wm2[1] = wm;
    float2a sm2; sm2[0] = sm; sm2[1] = sm;
    float2a f0 = bf2(v.x), f1 = bf2(v.y), f2v = bf2(v.z), f3 = bf2(v.w);
    aw2[0] += wm2 * f0; aw2[1] += wm2 * f1;
    aw2[2] += wm2 * f2v; aw2[3] += wm2 * f3;
    ap2[0] += sm2 * f0; ap2[1] += sm2 * f1;
    ap2[2] += sm2 * f2v; ap2[3] += sm2 * f3;
}

// ---------------- prep: W12T (256x384), W2cT (256x512), vs/vd = W_gat@att ----------------
__global__ void prep(const float* __restrict__ W_gat, const float* __restrict__ W1l,
                     const float* __restrict__ W1r, const float* __restrict__ W2l,
                     const float* __restrict__ W2r,
                     const float* __restrict__ att_s, const float* __restrict__ att_d,
                     unsigned short* __restrict__ W12T, unsigned short* __restrict__ W2cT,
                     float* __restrict__ vs, float* __restrict__ vd)
{
    int idx = blockIdx.x * 256 + threadIdx.x;
    if (idx < 98304) {                                   // W12T[c*384+k]
        int c = idx / 384, k = idx - c * 384;
        float v = 0.f;
        if (c < 128) { if (k < 128) v = W_gat[k * 128 + c]; }
        else {
            int cc = c - 128;
            if (k >= 256)       v = W1r[(k - 256) * 128 + cc];
            else if (k >= 128)  v = W1l[(k - 128) * 128 + cc];
        }
        W12T[idx] = f2bf(v);
    } else if (idx < 229376) {                           // W2cT[c*512+k]
        int t = idx - 98304;
        int c = t >> 9, k = t & 511;
        float v = (k < 256) ? W2l[k * 256 + c] : W2r[(k - 256) * 256 + c];
        W2cT[t] = f2bf(v);
    } else if (idx < 229376 + 128) {
        int k = idx - 229376;
        float s = 0.f, d = 0.f;
        for (int c = 0; c < 128; ++c) {
            float w = W_gat[k * 128 + c];
            s += w * att_s[c]; d += w * att_d[c];
        }
        vs[k] = s; vd[k] = d;
    }
}

// ---------------- conv x -> bf16 (combo3[:,256:384]) + attention logits (wave per node) ----------------
__global__ __launch_bounds__(256) void conv_x_asad(
    const float* __restrict__ x, const float* __restrict__ vs, const float* __restrict__ vd,
    unsigned short* __restrict__ combo3, float* __restrict__ as_, float* __restrict__ ad_, int N)
{
    const int wave = threadIdx.x >> 6, lane = threadIdx.x & 63;
    const int i = blockIdx.x * 4 + wave;
    if (i >= N) return;
    float2 xv = *(const float2*)(x + (size_t)i * 128 + 2 * lane);
    float2 vsv = *(const float2*)(vs + 2 * lane);
    float2 vdv = *(const float2*)(vd + 2 * lane);
    float s = xv.x * vsv.x + xv.y * vsv.y;
    float d = xv.x * vdv.x + xv.y * vdv.y;
    #pragma unroll
    for (int off = 32; off > 0; off >>= 1) {
        s += __shfl_xor(s, off);
        d += __shfl_xor(d, off);
    }
    if (lane == 0) { as_[i] = s; ad_[i] = d; }
    unsigned pk = (unsigned)f2bf(xv.x) | ((unsigned)f2bf(xv.y) << 16);
    *(unsigned*)(combo3 + (size_t)i * 384 + 256 + 2 * lane) = pk;
}

// ---------------- CSR build via 2-level bucket sort (no global atomics) ----------------
__global__ __launch_bounds__(256) void radix_hist(
    const int* __restrict__ dst, int E, int* __restrict__ blockhist, int B)
{
    const int blk = blockIdx.x, t = threadIdx.x;
    __shared__ int hist[256];
    hist[t] = 0; __syncthreads();
    const int chunk = blk * CA, cend = min(chunk + CA, E);
    for (int j = chunk + t; j < cend; j += 256)
        atomicAdd(&hist[((unsigned)dst[j]) >> 8], 1);
    __syncthreads();
    blockhist[t * B + blk] = hist[t];       // bin-major layout
}

__global__ __launch_bounds__(256) void scan_rows(
    int* __restrict__ blockhist, int B, int* __restrict__ bintot)
{
    const int bin = blockIdx.x, t = threadIdx.x;
    __shared__ int tmp[256];
    __shared__ int carry;
    if (t == 0) carry = 0;
    __syncthreads();
    const int base = bin * B;
    for (int off0 = 0; off0 < B; off0 += 256) {
        int i = off0 + t;
        int v = (i < B) ? blockhist[base + i] : 0;
        tmp[t] = v; __syncthreads();
        for (int off = 1; off < 256; off <<= 1) {
            int a = (t >= off) ? tmp[t - off] : 0;
            __syncthreads();
            tmp[t] += a;
            __syncthreads();
        }
        int incl = tmp[t] + carry;
        if (i < B) blockhist[base + i] = incl - v;
        __syncthreads();
        if (t == 255) carry = incl;
        __syncthreads();
    }
    if (t == 0) bintot[bin] = carry;
}

__global__ __launch_bounds__(256) void scan_bins(
    const int* __restrict__ bintot, int* __restrict__ bucket_base, int E)
{
    const int t = threadIdx.x;
    __shared__ int tmp[256];
    int v = bintot[t];
    tmp[t] = v; __syncthreads();
    for (int off = 1; off < 256; off <<= 1) {
        int a = (t >= off) ? tmp[t - off] : 0;
        __syncthreads();
        tmp[t] += a;
        __syncthreads();
    }
    bucket_base[t] = tmp[t] - v;
    if (t == 255) bucket_base[256] = E;
}

__global__ __launch_bounds__(256) void radix_scatter(
    const int* __restrict__ src, const int* __restrict__ dst, int E,
    const int* __restrict__ rowscan, const int* __restrict__ bucket_base,
    int B, unsigned int* __restrict__ srt)
{
    const int blk = blockIdx.x, t = threadIdx.x;
    __shared__ int hist[256], lscan[256], lcur[256], gbase[256];
    __shared__ unsigned int recs[CA];
    hist[t] = 0; __syncthreads();
    const int chunk = blk * CA, cend = min(chunk + CA, E);
    for (int j = chunk + t; j < cend; j += 256)
        atomicAdd(&hist[((unsigned)dst[j]) >> 8], 1);
    __syncthreads();
    lscan[t] = hist[t]; __syncthreads();
    for (int off = 1; off < 256; off <<= 1) {
        int a = (t >= off) ? lscan[t - off] : 0;
        __syncthreads();
        lscan[t] += a;
        __syncthreads();
    }
    int excl = lscan[t] - hist[t];
    __syncthreads();
    lscan[t] = excl; lcur[t] = excl;
    gbase[t] = bucket_base[t] + rowscan[t * B + blk];
    __syncthreads();
    for (int j = chunk + t; j < cend; j += 256) {
        int d = dst[j];
        unsigned int r = ((unsigned)d << 16) | (unsigned)src[j];
        int p = atomicAdd(&lcur[((unsigned)d) >> 8], 1);
        recs[p] = r;
    }
    __syncthreads();
    const int cnt = cend - chunk;
    for (int k = t; k < cnt; k += 256) {
        unsigned int r = recs[k];
        int bin = r >> 24;
        srt[gbase[bin] + (k - lscan[bin])] = r;
    }
}

__global__ __launch_bounds__(256) void bucket_sort(
    const unsigned int* __restrict__ srt, const int* __restrict__ bucket_base,
    unsigned short* __restrict__ col_src, int* __restrict__ rp, int N, int E)
{
    const int b = blockIdx.x, t = threadIdx.x;
    const int beg = bucket_base[b], end = bucket_base[b + 1];
    const int cnt = end - beg;
    __shared__ int hist[256], lscan[256], lcur[256];
    __shared__ unsigned int recs[CAPB];
    __shared__ unsigned short outr[CAPB];
    hist[t] = 0; __syncthreads();
    const bool fits = cnt <= CAPB;
    if (fits) {
        for (int j = beg + t; j < end; j += 256) {
            unsigned int r = srt[j];
            recs[j - beg] = r;
            atomicAdd(&hist[(r >> 16) & 255], 1);
        }
    } else {
        for (int j = beg + t; j < end; j += 256)
            atomicAdd(&hist[(srt[j] >> 16) & 255], 1);
    }
    __syncthreads();
    lscan[t] = hist[t]; __syncthreads();
    for (int off = 1; off < 256; off <<= 1) {
        int a = (t >= off) ? lscan[t - off] : 0;
        __syncthreads();
        lscan[t] += a;
        __syncthreads();
    }
    int excl = lscan[t] - hist[t];
    __syncthreads();
    lscan[t] = excl; lcur[t] = excl;
    int d = (b << 8) + t;
    if (d < N) rp[d] = beg + excl;
    if (b == gridDim.x - 1 && t == 0) rp[N] = E;
    __syncthreads();
    if (fits) {
        for (int k = t; k < cnt; k += 256) {
            unsigned int r = recs[k];
            int p = atomicAdd(&lcur[(r >> 16) & 255], 1);
            outr[p] = (unsigned short)(r & 0xFFFFu);
        }
        __syncthreads();
        for (int k = t; k < cnt; k += 256)
            col_src[beg + k] = outr[k];
    } else {
        for (int j = beg + t; j < end; j += 256) {
            unsigned int r = srt[j];
            int p = atomicAdd(&lcur[(r >> 16) & 255], 1);
            col_src[beg + p] = (unsigned short)(r & 0xFFFFu);
        }
    }
}

// ---------------- fused GAT-weighted mean + SAGE1 mean over x (bf16 payload) ----------------
// 2 nodes per wave: lanes 0-31 = node A, 32-63 = node B; 2 groups of 16 per node.
__global__ __launch_bounds__(256) void gat_sage1(
    const int* __restrict__ row_ptr, const unsigned short* __restrict__ col_src,
    const float* __restrict__ as_, const float* __restrict__ ad_,
    unsigned short* __restrict__ combo3, int N)
{
    const int wave = threadIdx.x >> 6, lane = threadIdx.x & 63;
    const int half = lane >> 5, hl = lane & 31;
    const int g2 = (lane >> 4) & 1, l15 = lane & 15;
    const int h32 = half << 5;
    const int i = blockIdx.x * 8 + wave * 2 + half;
    const bool valid = i < N;

    const int beg = valid ? row_ptr[i] : 0;
    const int end = valid ? row_ptr[i + 1] : 0;
    const int deg = end - beg;
    const float adi = valid ? ad_[i] : 0.f;
    const float wself = valid ? __expf(lrelu(as_[i] + adi)) : 0.f;

    int j = beg + hl;
    int sn_l = (j < end) ? (int)col_src[j] : 0;
    float w_l = (j < end) ? __expf(lrelu(as_[sn_l] + adi)) : 0.f;
    int o_l = sn_l * 768;                      // pre-scaled row byte-offset

    const char* cb = (const char*)combo3;
    const unsigned lo = 512u + 16u * (unsigned)l15;   // x-part col slice within row

    uint4 sv = ld16(cb, (unsigned)(valid ? i : 0) * 768u + lo);
    const int dc = deg < 32 ? deg : 32;
    const int nr = dc >> 2;                    // full 4-edge rounds (2 per group)
    uint4 pv0, pv1; float pw0 = 0.f, pw1 = 0.f;
    if (nr > 0) {
        int so0 = __shfl(o_l, h32 + g2), so1 = __shfl(o_l, h32 + 2 + g2);
        pw0 = __shfl(w_l, h32 + g2); pw1 = __shfl(w_l, h32 + 2 + g2);
        pv0 = ld16(cb, lo + (unsigned)so0);
        pv1 = ld16(cb, lo + (unsigned)so1);
    }

    float2a aw2[4], ap2[4];
    {   // self term (weighted only; g2==0 carries it)
        float wm = (g2 == 0) ? wself : 0.f;
        float2a wm2; wm2[0] = wm; wm2[1] = wm;
        aw2[0] = wm2 * bf2(sv.x); aw2[1] = wm2 * bf2(sv.y);
        aw2[2] = wm2 * bf2(sv.z); aw2[3] = wm2 * bf2(sv.w);
        #pragma unroll
        for (int k = 0; k < 4; ++k) { ap2[k][0] = 0.f; ap2[k][1] = 0.f; }
    }

    for (int r = 0; r < nr; ++r) {             // prefetched 4-edge rounds
        uint4 cv0 = pv0, cv1 = pv1;
        float cw0 = pw0, cw1 = pw1;
        if (r + 1 < nr) {
            int b4 = (r + 1) * 4;
            int so0 = __shfl(o_l, h32 + b4 + g2), so1 = __shfl(o_l, h32 + b4 + 2 + g2);
            pw0 = __shfl(w_l, h32 + b4 + g2); pw1 = __shfl(w_l, h32 + b4 + 2 + g2);
            pv0 = ld16(cb, lo + (unsigned)so0);
            pv1 = ld16(cb, lo + (unsigned)so1);
        }
        accb(aw2, ap2, cw0, cv0);
        accb(aw2, ap2, cw1, cv1);
    }
    for (int j2 = nr * 4; j2 < dc; j2 += 2) {  // masked pair tail
        int eidx = j2 + g2;
        bool val = eidx < dc;
        int so  = __shfl(o_l, h32 + (val ? eidx : 0));
        float w = __shfl(w_l, h32 + (val ? eidx : 0));
        uint4 v = ld16(cb, lo + (unsigned)so);
        accbm(aw2, ap2, val ? w : 0.f, val ? 1.f : 0.f, v);
    }
    for (int j3 = 32; j3 < deg; ++j3) {        // rare tail (deg > 32), gather part
        int sn = col_src[beg + j3];
        float w = __expf(lrelu(as_[sn] + adi));
        uint4 v = ld16(cb, lo + (unsigned)(sn * 768));
        accbm(aw2, ap2, (g2 == 0) ? w : 0.f, (g2 == 0) ? 1.f : 0.f, v);
    }

    // denominator: per-lane partial (32 edges/half) + rare tail, then 5-level half-reduce
    float s = w_l;
    for (int jj = beg + hl + 32; jj < end; jj += 32)
        s += __expf(lrelu(as_[col_src[jj]] + adi));
    #pragma unroll
    for (int off = 16; off > 0; off >>= 1) s += __shfl_xor(s, off);
    const float denom = s + wself;

    float aw[8], ap[8];
    #pragma unroll
    for (int k = 0; k < 4; ++k) {
        aw[2 * k] = aw2[k][0]; aw[2 * k + 1] = aw2[k][1];
        ap[2 * k] = ap2[k][0]; ap[2 * k + 1] = ap2[k][1];
    }
    #pragma unroll
    for (int k = 0; k < 8; ++k) {              // single cross-group combine (within half)
        aw[k] += __shfl_xor(aw[k], 16);
        ap[k] += __shfl_xor(ap[k], 16);
    }
    if (valid && g2 == 0) {     // wx -> combo3[:,0:128]
        float inv = 1.f / denom;
        uint4 pk;
        pk.x = (unsigned)f2bf(aw[0] * inv) | ((unsigned)f2bf(aw[1] * inv) << 16);
        pk.y = (unsigned)f2bf(aw[2] * inv) | ((unsigned)f2bf(aw[3] * inv) << 16);
        pk.z = (unsigned)f2bf(aw[4] * inv) | ((unsigned)f2bf(aw[5] * inv) << 16);
        pk.w = (unsigned)f2bf(aw[6] * inv) | ((unsigned)f2bf(aw[7] * inv) << 16);
        *(uint4*)(combo3 + (size_t)i * 384 + 8 * l15) = pk;
    } else if (valid && g2 == 1) {  // agg1 -> combo3[:,128:256]
        float dinv = 1.f / fmaxf((float)deg, 1.f);
        uint4 pk;
        pk.x = (unsigned)f2bf(ap[0] * dinv) | ((unsigned)f2bf(ap[1] * dinv) << 16);
        pk.y = (unsigned)f2bf(ap[2] * dinv) | ((unsigned)f2bf(ap[3] * dinv) << 16);
        pk.z = (unsigned)f2bf(ap[4] * dinv) | ((unsigned)f2bf(ap[5] * dinv) << 16);
        pk.w = (unsigned)f2bf(ap[6] * dinv) | ((unsigned)f2bf(ap[7] * dinv) << 16);
        *(uint4*)(combo3 + (size_t)i * 384 + 128 + 8 * l15) = pk;
    }
}

// swizzled staging column for lane slot v: global kk block to fetch
__device__ __forceinline__ int swz_kk(int v) {
    return (((v & 7) ^ ((v >> 3) & 7)) * 8);
}

// ---------------- GEMM h = combo3 @ W12T^T + bias, fused LN1+ReLU -> bf16 h + fp8 hq ----------------
// BM=64, BN=256, BK=64, K=384. XOR-swizzled LDS. K-split by wave (skips W12T zero block).
__global__ __launch_bounds__(256) void gemm12_ln(
    const unsigned short* __restrict__ combo3, int M,
    const unsigned short* __restrict__ W12T,
    const float* __restrict__ b_gat, const float* __restrict__ b1l,
    const float* __restrict__ g1, const float* __restrict__ bb1,
    unsigned short* __restrict__ combo2, unsigned char* __restrict__ hq)
{
    __shared__ __align__(16) unsigned short As[64 * 64];
    __shared__ __align__(16) unsigned short Ws[256 * 64];   // staging uses first 128x64; Hs repack uses all
    const int tid = threadIdx.x;
    const int bm = blockIdx.x * 64;
    const int wave = tid >> 6, lane = tid & 63;
    const int quad = lane >> 4, l15 = lane & 15;
    const int swz_rd = (l15 & 7) * 8;          // read-side XOR

    float4a acc[4][4];
    const float4a z4 = {0.f, 0.f, 0.f, 0.f};
    #pragma unroll
    for (int i = 0; i < 4; ++i)
        #pragma unroll
        for (int j = 0; j < 4; ++j) acc[i][j] = z4;

    for (int k0 = 0; k0 < 384; k0 += 64) {
        const bool low = k0 < 128;
        const int rbase = low ? 0 : 128;       // active output-col half for this K-step
        #pragma unroll
        for (int it = 0; it < 2; ++it) {
            int v = tid + it * 256;
            int r = v >> 3, kk = swz_kk(v);
            if (bm + r < M)
                load_lds16(combo3 + (size_t)(bm + r) * 384 + k0 + kk, &As[v * 8]);
        }
        #pragma unroll
        for (int it = 0; it < 4; ++it) {       // stage only the active 128-row half of W12T
            int v = tid + it * 256;            // 0..1023: rloc 0..127
            int r = v >> 3, kk = swz_kk(v);
            load_lds16(W12T + (size_t)(rbase + r) * 384 + k0 + kk, &Ws[v * 8]);
        }
        __syncthreads();
        if ((wave < 2) == low) {               // wave active only in its K-range
            #pragma unroll
            for (int ks = 0; ks < 64; ks += 32) {
                short8 af[4], bfr[4];
                #pragma unroll
                for (int i = 0; i < 4; ++i)
                    af[i] = *(const short8*)(&As[(i * 16 + l15) * 64 + ((ks + quad * 8) ^ swz_rd)]);
                #pragma unroll
                for (int j = 0; j < 4; ++j)
                    bfr[j] = *(const short8*)(&Ws[((wave & 1) * 64 + j * 16 + l15) * 64 + ((ks + quad * 8) ^ swz_rd)]);
                #pragma unroll
                for (int i = 0; i < 4; ++i)
                    #pragma unroll
                    for (int j = 0; j < 4; ++j)
                        acc[i][j] = __builtin_amdgcn_mfma_f32_16x16x32_bf16(af[i], bfr[j], acc[i][j], 0, 0, 0);
            }
        }
        __syncthreads();
    }
    // epilogue: bias + LN + ReLU
    int col[4]; float bcol[4], gc[4], bc2[4];
    #pragma unroll
    for (int j = 0; j < 4; ++j) {
        int c = wave * 64 + j * 16 + l15;
        col[j] = c;
        bcol[j] = (c < 128) ? b_gat[c] : b1l[c - 128];
        gc[j] = g1[c]; bc2[j] = bb1[c];
    }
    float* lsum = (float*)As;         // 256 floats
    float* lsq  = lsum + 256;         // 256 floats
    #pragma unroll
    for (int i = 0; i < 4; ++i)
        #pragma unroll
        for (int r = 0; r < 4; ++r) {
            float ps = 0.f, pq = 0.f;
            #pragma unroll
            for (int j = 0; j < 4; ++j) {
                float v = acc[i][j][r] + bcol[j];
                ps += v; pq += v * v;
            }
            #pragma unroll
            for (int off = 1; off < 16; off <<= 1) {
                ps += __shfl_xor(ps, off);
                pq += __shfl_xor(pq, off);
            }
            if (l15 == 0) {
                int row = i * 16 + quad * 4 + r;
                lsum[row * 4 + wave] = ps;
                lsq[row * 4 + wave]  = pq;
            }
        }
    __syncthreads();
    unsigned short* Hs = Ws;          // 64 x 256 bf16 repack buffer
    #pragma unroll
    for (int i = 0; i < 4; ++i)
        #pragma unroll
        for (int r = 0; r < 4; ++r) {
            int row = i * 16 + quad * 4 + r;
            float su = lsum[row * 4] + lsum[row * 4 + 1] + lsum[row * 4 + 2] + lsum[row * 4 + 3];
            float sq = lsq[row * 4] + lsq[row * 4 + 1] + lsq[row * 4 + 2] + lsq[row * 4 + 3];
            float mu = su * (1.f / 256.f);
            float var = sq * (1.f / 256.f) - mu * mu;
            float rs = rsqrtf(var + LN_EPS);
            #pragma unroll
            for (int j = 0; j < 4; ++j) {
                float v = acc[i][j][r] + bcol[j];
                float o = fmaxf((v - mu) * rs * gc[j] + bc2[j], 0.f);
                Hs[row * 256 + col[j]] = f2bf(o);
            }
        }
    __syncthreads();
    #pragma unroll
    for (int it = 0; it < 8; ++it) {        // bf16 h -> combo2[:,256:512]
        int v = tid + it * 256;
        int r = v >> 5, cc = (v & 31) * 8;
        if (bm + r < M)
            *(uint4*)(combo2 + (size_t)(bm + r) * 512 + 256 + cc) = *(const uint4*)(&Hs[r * 256 + cc]);
    }
    #pragma unroll
    for (int it = 0; it < 4; ++it) {        // fp8 h -> hq (gather payload)
        int v = tid + it * 256;
        int r = v >> 4, c16 = (v & 15) * 16;
        if (bm + r < M) {
            uint4 o;
            #pragma unroll
            for (int q = 0; q < 4; ++q) {
                unsigned int w0 = *(const unsigned int*)(&Hs[r * 256 + c16 + q * 4 + 0]);
                unsigned int w1 = *(const unsigned int*)(&Hs[r * 256 + c16 + q * 4 + 2]);
                unsigned int t0 = __builtin_amdgcn_cvt_pk_fp8_f32(bflo(w0), bfhi(w0), 0, false);
                unsigned int t1 = __builtin_amdgcn_cvt_pk_fp8_f32(bflo(w1), bfhi(w1), t0, true);
                ((unsigned int*)&o)[q] = t1;
            }
            *(uint4*)(hq + (size_t)(bm + r) * 256 + c16) = o;
        }
    }
}

// ---------------- SAGE2 mean aggregate over fp8 hq (2 nodes per wave, half-split) ----------------
__global__ __launch_bounds__(256) void sage2_agg(
    const int* __restrict__ row_ptr, const unsigned short* __restrict__ col_src,
    const unsigned char* __restrict__ hq, unsigned short* __restrict__ combo2, int N)
{
    const int wave = threadIdx.x >> 6, lane = threadIdx.x & 63;
    const int half = lane >> 5, hl = lane & 31;
    const int g2 = (lane >> 4) & 1, l15 = lane & 15;
    const int h32 = half << 5;
    const int i = blockIdx.x * 8 + wave * 2 + half;
    const bool valid = i < N;

    const int beg = valid ? row_ptr[i] : 0;
    const int end = valid ? row_ptr[i + 1] : 0;
    const int deg = end - beg;
    int cidx = (beg + hl < end) ? (int)col_src[beg + hl] : 0;
    int o_l = cidx * 256;                      // pre-scaled row byte-offset
    const char* hb = (const char*)hq;
    const unsigned lo = 16u * (unsigned)l15;
    float2a a2[8];
    #pragma unroll
    for (int k = 0; k < 8; ++k) { a2[k][0] = 0.f; a2[k][1] = 0.f; }
    const int dc = deg < 32 ? deg : 32;
    int j = 0;
    for (; j + 4 <= dc; j += 4) {          // unmasked 4-edge rounds (2 per group)
        #pragma unroll
        for (int u = 0; u < 2; ++u) {
            int eidx = j + 2 * u + g2;
            int so = __shfl(o_l, h32 + eidx);
            uint4 v = ld16(hb, lo + (unsigned)so);
            a2[0] += __builtin_amdgcn_cvt_pk_f32_fp8(v.x, false);
            a2[1] += __builtin_amdgcn_cvt_pk_f32_fp8(v.x, true);
            a2[2] += __builtin_amdgcn_cvt_pk_f32_fp8(v.y, false);
            a2[3] += __builtin_amdgcn_cvt_pk_f32_fp8(v.y, true);
            a2[4] += __builtin_amdgcn_cvt_pk_f32_fp8(v.z, false);
            a2[5] += __builtin_amdgcn_cvt_pk_f32_fp8(v.z, true);
            a2[6] += __builtin_amdgcn_cvt_pk_f32_fp8(v.w, false);
            a2[7] += __builtin_amdgcn_cvt_pk_f32_fp8(v.w, true);
        }
    }
    for (; j < dc; j += 2) {               // masked pair tail
        int eidx = j + g2;
        bool val = eidx < dc;
        int so = __shfl(o_l, h32 + (val ? eidx : 0));
        uint4 v = ld16(hb, lo + (unsigned)so);
        float mlt = val ? 1.f : 0.f;
        float2a m2; m2[0] = mlt; m2[1] = mlt;
        a2[0] += m2 * __builtin_amdgcn_cvt_pk_f32_fp8(v.x, false);
        a2[1] += m2 * __builtin_amdgcn_cvt_pk_f32_fp8(v.x, true);
        a2[2] += m2 * __builtin_amdgcn_cvt_pk_f32_fp8(v.y, false);
        a2[3] += m2 * __builtin_amdgcn_cvt_pk_f32_fp8(v.y, true);
        a2[4] += m2 * __builtin_amdgcn_cvt_pk_f32_fp8(v.z, false);
        a2[5] += m2 * __builtin_amdgcn_cvt_pk_f32_fp8(v.z, true);
        a2[6] += m2 * __builtin_amdgcn_cvt_pk_f32_fp8(v.w, false);
        a2[7] += m2 * __builtin_amdgcn_cvt_pk_f32_fp8(v.w, true);
    }
    for (int j3 = 32; j3 < deg; ++j3) {    // rare tail (deg > 32)
        int sn = col_src[beg + j3];
        uint4 v = ld16(hb, lo + (unsigned)(sn * 256));
        float mlt = (g2 == 0) ? 1.f : 0.f;
        float2a m2; m2[0] = mlt; m2[1] = mlt;
        a2[0] += m2 * __builtin_amdgcn_cvt_pk_f32_fp8(v.x, false);
        a2[1] += m2 * __builtin_amdgcn_cvt_pk_f32_fp8(v.x, true);
        a2[2] += m2 * __builtin_amdgcn_cvt_pk_f32_fp8(v.y, false);
        a2[3] += m2 * __builtin_amdgcn_cvt_pk_f32_fp8(v.y, true);
        a2[4] += m2 * __builtin_amdgcn_cvt_pk_f32_fp8(v.z, false);
        a2[5] += m2 * __builtin_amdgcn_cvt_pk_f32_fp8(v.z, true);
        a2[6] += m2 * __builtin_amdgcn_cvt_pk_f32_fp8(v.w, false);
        a2[7] += m2 * __builtin_amdgcn_cvt_pk_f32_fp8(v.w, true);
    }
    float a[16];
    #pragma unroll
    for (int k = 0; k < 8; ++k) { a[2 * k] = a2[k][0]; a[2 * k + 1] = a2[k][1]; }
    #pragma unroll
    for (int k = 0; k < 16; ++k)               // single cross-group combine (within half)
        a[k] += __shfl_xor(a[k], 16);
    if (valid && g2 == 0) {
        float dinv = 1.f / fmaxf((float)deg, 1.f);
        uint4 pk0, pk1;
        pk0.x = (unsigned)f2bf(a[0] * dinv)  | ((unsigned)f2bf(a[1] * dinv)  << 16);
        pk0.y = (unsigned)f2bf(a[2] * dinv)  | ((unsigned)f2bf(a[3] * dinv)  << 16);
        pk0.z = (unsigned)f2bf(a[4] * dinv)  | ((unsigned)f2bf(a[5] * dinv)  << 16);
        pk0.w = (unsigned)f2bf(a[6] * dinv)  | ((unsigned)f2bf(a[7] * dinv)  << 16);
        pk1.x = (unsigned)f2bf(a[8] * dinv)  | ((unsigned)f2bf(a[9] * dinv)  << 16);
        pk1.y = (unsigned)f2bf(a[10] * dinv) | ((unsigned)f2bf(a[11] * dinv) << 16);
        pk1.z = (unsigned)f2bf(a[12] * dinv) | ((unsigned)f2bf(a[13] * dinv) << 16);
        pk1.w = (unsigned)f2bf(a[14] * dinv) | ((unsigned)f2bf(a[15] * dinv) << 16);
        *(uint4*)(combo2 + (size_t)i * 512 + 16 * l15)     = pk0;
        *(uint4*)(combo2 + (size_t)i * 512 + 16 * l15 + 8) = pk1;
    }
}

// ---------------- GEMM h2 = combo2 @ W2cT^T + b2l, fused LN2+ReLU+classifier -> out ----------------
// BM=64, BN=256, BK=64, K=512; 8 waves x 32 cols each (acc[4][2]) -> 2x resident waves,
// latency-bound regime (R10 counters: all pipes <12%) fixed by occupancy, not tile size.
__global__ __launch_bounds__(512) void gemm3_out(
    const unsigned short* __restrict__ combo2, int M,
    const unsigned short* __restrict__ W2cT,
    const float* __restrict__ b2l,
    const float* __restrict__ g2, const float* __restrict__ bb2,
    const float* __restrict__ Wc, const float* __restrict__ bc,
    float* __restrict__ out)
{
    __shared__ __align__(16) unsigned short As[64 * 64];
    __shared__ __align__(16) unsigned short Ws[256 * 64];
    const int tid = threadIdx.x;
    const int bm = blockIdx.x * 64;
    const int wave = tid >> 6, lane = tid & 63;
    const int quad = lane >> 4, l15 = lane & 15;
    const int swz_rd = (l15 & 7) * 8;

    float4a acc[4][2];
    const float4a z4 = {0.f, 0.f, 0.f, 0.f};
    #pragma unroll
    for (int i = 0; i < 4; ++i)
        #pragma unroll
        for (int j = 0; j < 2; ++j) acc[i][j] = z4;

    for (int k0 = 0; k0 < 512; k0 += 64) {
        {   // stage As: 512 threads x 1 load
            int v = tid;
            int r = v >> 3, kk = swz_kk(v);
            if (bm + r < M)
                load_lds16(combo2 + (size_t)(bm + r) * 512 + k0 + kk, &As[v * 8]);
        }
        #pragma unroll
        for (int it = 0; it < 4; ++it) {   // stage Ws: 512 threads x 4 loads
            int v = tid + it * 512;
            int r = v >> 3, kk = swz_kk(v);
            load_lds16(W2cT + (size_t)r * 512 + k0 + kk, &Ws[v * 8]);
        }
        __syncthreads();
        #pragma unroll
        for (int ks = 0; ks < 64; ks += 32) {
            short8 af[4], bfr[2];
            #pragma unroll
            for (int i = 0; i < 4; ++i)
                af[i] = *(const short8*)(&As[(i * 16 + l15) * 64 + ((ks + quad * 8) ^ swz_rd)]);
            #pragma unroll
            for (int j = 0; j < 2; ++j)
                bfr[j] = *(const short8*)(&Ws[(wave * 32 + j * 16 + l15) * 64 + ((ks + quad * 8) ^ swz_rd)]);
            #pragma unroll
            for (int i = 0; i < 4; ++i)
                #pragma unroll
                for (int j = 0; j < 2; ++j)
                    acc[i][j] = __builtin_amdgcn_mfma_f32_16x16x32_bf16(af[i], bfr[j], acc[i][j], 0, 0, 0);
        }
        __syncthreads();
    }
    int col[2]; float bcol[2], gc[2], bc2[2], wcl[2];
    #pragma unroll
    for (int j = 0; j < 2; ++j) {
        int c = wave * 32 + j * 16 + l15;
        col[j] = c;
        bcol[j] = b2l[c];
        gc[j] = g2[c]; bc2[j] = bb2[c]; wcl[j] = Wc[c];
    }
    float* lsum = (float*)As;          // 512 floats
    float* lsq  = lsum + 512;          // 512 floats
    float* ldot = lsum + 1024;         // 512 floats
    #pragma unroll
    for (int i = 0; i < 4; ++i)
        #pragma unroll
        for (int r = 0; r < 4; ++r) {
            float ps = 0.f, pq = 0.f;
            #pragma unroll
            for (int j = 0; j < 2; ++j) {
                float v = acc[i][j][r] + bcol[j];
                ps += v; pq += v * v;
            }
            #pragma unroll
            for (int off = 1; off < 16; off <<= 1) {
                ps += __shfl_xor(ps, off);
                pq += __shfl_xor(pq, off);
            }
            if (l15 == 0) {
                int row = i * 16 + quad * 4 + r;
                lsum[row * 8 + wave] = ps;
                lsq[row * 8 + wave]  = pq;
            }
        }
    __syncthreads();
    #pragma unroll
    for (int i = 0; i < 4; ++i)
        #pragma unroll
        for (int r = 0; r < 4; ++r) {
            int row = i * 16 + quad * 4 + r;
            float su = 0.f, sq = 0.f;
            #pragma unroll
            for (int w8 = 0; w8 < 8; ++w8) {
                su += lsum[row * 8 + w8];
                sq += lsq[row * 8 + w8];
            }
            float mu = su * (1.f / 256.f);
            float var = sq * (1.f / 256.f) - mu * mu;
            float rs = rsqrtf(var + LN_EPS);
            float pd = 0.f;
            #pragma unroll
            for (int j = 0; j < 2; ++j) {
                float v = acc[i][j][r] + bcol[j];
                float o = fmaxf((v - mu) * rs * gc[j] + bc2[j], 0.f);
                pd += o * wcl[j];
            }
            #pragma unroll
            for (int off = 1; off < 16; off <<= 1) pd += __shfl_xor(pd, off);
            if (l15 == 0) ldot[row * 8 + wave] = pd;
        }
    __syncthreads();
    if (tid < 64 && bm + tid < M) {
        float o = bc[0];
        #pragma unroll
        for (int w8 = 0; w8 < 8; ++w8) o += ldot[tid * 8 + w8];
        out[bm + tid] = o;
    }
}

extern "C" void kernel_launch(void* const* d_in, const int* in_sizes, int n_in,
                              void* d_out, int out_size, void* d_ws, size_t ws_size,
                              hipStream_t stream)
{
    const float* x     = (const float*)d_in[0];
    const int*   ei    = (const int*)d_in[1];
    const float* W_gat = (const float*)d_in[2];
    const float* att_s = (const float*)d_in[3];
    const float* att_d = (const float*)d_in[4];
    const float* b_gat = (const float*)d_in[5];
    const float* W1l   = (const float*)d_in[6];
    const float* b1l   = (const float*)d_in[7];
    const float* W1r   = (const float*)d_in[8];
    const float* ln1g  = (const float*)d_in[9];
    const float* ln1b  = (const float*)d_in[10];
    const float* W2l   = (const float*)d_in[11];
    const float* b2l   = (const float*)d_in[12];
    const float* W2r   = (const float*)d_in[13];
    const float* ln2g  = (const float*)d_in[14];
    const float* ln2b  = (const float*)d_in[15];
    const float* Wc    = (const float*)d_in[16];
    const float* bc    = (const float*)d_in[17];

    const int N = in_sizes[0] / 128;
    const int E = in_sizes[1] / 2;
    const int* srcp = ei;
    const int* dstp = ei + E;

    char* p = (char*)d_ws;
    unsigned short* combo3 = (unsigned short*)p; p += (size_t)N * 384 * 2;  // [wx | agg1 | x_bf]
    unsigned short* combo2 = (unsigned short*)p; p += (size_t)N * 512 * 2;  // [agg2 | h_ln]
    unsigned char* hq     = (unsigned char*)p;  p += (size_t)N * 256;       // fp8 h (gather payload)
    float* as_    = (float*)p;                 p += (size_t)N * 4;
    float* ad_    = (float*)p;                 p += (size_t)N * 4;
    float* vs     = (float*)p;                 p += 128 * 4;
    float* vd     = (float*)p;                 p += 128 * 4;
    unsigned short* W12T = (unsigned short*)p; p += (size_t)256 * 384 * 2;
    unsigned short* W2cT = (unsigned short*)p; p += (size_t)256 * 512 * 2;
    unsigned int* srt    = (unsigned int*)p;   p += (size_t)E * 4;
    unsigned short* col_src = (unsigned short*)p; p += (((size_t)E * 2 + 15) & ~15ull);
    int* rp       = (int*)p;                   p += (size_t)(N + 1) * 4;
    const int B   = (E + CA - 1) / CA;         // radix blocks
    int* blockhist = (int*)p;                  p += (size_t)256 * B * 4;
    int* bucket_base = (int*)p;                p += 257 * 4;
    int* bintot   = (int*)p;                   p += 256 * 4;

    dim3 b256(256);
    const int mb64 = (N + 63) / 64;
    const int nb = (N + 255) >> 8;             // coarse buckets
    const int prep_total = 229376 + 128;

    // --- prep + x conversion/logits ---
    hipLaunchKernelGGL(prep, dim3((prep_total + 255) / 256), b256, 0, stream,
                       W_gat, W1l, W1r, W2l, W2r, att_s, att_d, W12T, W2cT, vs, vd);
    hipLaunchKernelGGL(conv_x_asad, dim3((N + 3) / 4), b256, 0, stream,
                       x, vs, vd, combo3, as_, ad_, N);

    // --- CSR by dst: bucket sort (no global atomics; 2-level parallel scan) ---
    hipLaunchKernelGGL(radix_hist, dim3(B), b256, 0, stream, dstp, E, blockhist, B);
    hipLaunchKernelGGL(scan_rows, dim3(256), b256, 0, stream, blockhist, B, bintot);
    hipLaunchKernelGGL(scan_bins, dim3(1), b256, 0, stream, bintot, bucket_base, E);
    hipLaunchKernelGGL(radix_scatter, dim3(B), b256, 0, stream,
                       srcp, dstp, E, blockhist, bucket_base, B, srt);
    hipLaunchKernelGGL(bucket_sort, dim3(nb), b256, 0, stream,
                       srt, bucket_base, col_src, rp, N, E);

    // --- GAT wmean + SAGE1 mean over x (2 nodes/wave half-split) ---
    hipLaunchKernelGGL(gat_sage1, dim3((N + 7) / 8), b256, 0, stream,
                       rp, col_src, as_, ad_, combo3, N);

    // --- h = combo3 @ W12T^T + bias, LN1+ReLU fused -> combo2[:,256:512] bf16 + hq fp8 ---
    hipLaunchKernelGGL(gemm12_ln, dim3(mb64), b256, 0, stream,
                       combo3, N, W12T, b_gat, b1l, ln1g, ln1b, combo2, hq);

    // --- SAGE2 aggregate (fp8 gather, 2 nodes/wave half-split) -> combo2[:,0:256] ---
    hipLaunchKernelGGL(sage2_agg, dim3((N + 7) / 8), b256, 0, stream,
                       rp, col_src, hq, combo2, N);

    // --- h2 GEMM (BM=64, 8 waves) + LN2 + ReLU + classifier -> out ---
    hipLaunchKernelGGL(gemm3_out, dim3(mb64), dim3(512), 0, stream,
                       combo2, N, W2cT, b2l, ln2g, ln2b, Wc, bc, (float*)d_out);
}

// Round 12
// 271.569 us; speedup vs baseline: 1.0728x; 1.0440x over previous
//
#include <hip/hip_runtime.h>

#define LN_EPS 1e-5f
#define CA 2048          // edges per block in radix pass
#define CAPB 6144        // per-bucket LDS record capacity (bucket ~ Poisson(4096))

typedef __attribute__((ext_vector_type(8))) short short8;
typedef __attribute__((ext_vector_type(4))) float float4a;
typedef __attribute__((ext_vector_type(2))) float float2a;

__device__ __forceinline__ float lrelu(float v) { return v > 0.f ? v : 0.2f * v; }

__device__ __forceinline__ unsigned short f2bf(float f) {
    union { float f; unsigned int u; } x; x.f = f;
    unsigned int u = x.u;
    unsigned int r = (u + 0x7fffu + ((u >> 16) & 1u)) >> 16;   // RNE
    return (unsigned short)r;
}
__device__ __forceinline__ float bflo(unsigned int v) {
    union { unsigned int u; float f; } x; x.u = v << 16; return x.f;
}
__device__ __forceinline__ float bfhi(unsigned int v) {
    union { unsigned int u; float f; } x; x.u = v & 0xffff0000u; return x.f;
}
// unpack dword of 2 bf16 -> packed float2 (feeds v_pk_fma_f32)
__device__ __forceinline__ float2a bf2(unsigned int w) {
    union { unsigned int u; float f; } lo, hi;
    lo.u = w << 16; hi.u = w & 0xffff0000u;
    float2a r; r[0] = lo.f; r[1] = hi.f; return r;
}

__device__ __forceinline__ void load_lds16(const void* g, void* l) {
    __builtin_amdgcn_global_load_lds(
        (const __attribute__((address_space(1))) void*)g,
        (__attribute__((address_space(3))) void*)l, 16, 0, 0);
}

// 16B load from uniform base + 32-bit byte offset
__device__ __forceinline__ uint4 ld16(const char* __restrict__ b, unsigned off) {
    return *(const uint4*)(b + off);
}

// unmasked bf16 dual-accumulate: aw += w*f, ap += f
__device__ __forceinline__ void accb(float2a aw2[4], float2a ap2[4], float w, uint4 v) {
    float2a wm2; wm2[0] = w; wm2[1] = w;
    float2a f0 = bf2(v.x), f1 = bf2(v.y), f2v = bf2(v.z), f3 = bf2(v.w);
    aw2[0] += wm2 * f0; aw2[1] += wm2 * f1;
    aw2[2] += wm2 * f2v; aw2[3] += wm2 * f3;
    ap2[0] += f0; ap2[1] += f1;
    ap2[2] += f2v; ap2[3] += f3;
}

// masked bf16 dual-accumulate
__device__ __forceinline__ void accbm(float2a aw2[4], float2a ap2[4], float wm, float sm, uint4 v) {
    float2a wm2; wm2[0] = wm; wm2[1] = wm;
    float2a sm2; sm2[0] = sm; sm2[1] = sm;
    float2a f0 = bf2(v.x), f1 = bf2(v.y), f2v = bf2(v.z), f3 = bf2(v.w);
    aw2[0] += wm2 * f0; aw2[1] += wm2 * f1;
    aw2[2] += wm2 * f2v; aw2[3] += wm2 * f3;
    ap2[0] += sm2 * f0; ap2[1] += sm2 * f1;
    ap2[2] += sm2 * f2v; ap2[3] += sm2 * f3;
}

// ---------------- prep: W12T (256x384), W2cT (256x512), vs/vd = W_gat@att ----------------
__global__ void prep(const float* __restrict__ W_gat, const float* __restrict__ W1l,
                     const float* __restrict__ W1r, const float* __restrict__ W2l,
                     const float* __restrict__ W2r,
                     const float* __restrict__ att_s, const float* __restrict__ att_d,
                     unsigned short* __restrict__ W12T, unsigned short* __restrict__ W2cT,
                     float* __restrict__ vs, float* __restrict__ vd)
{
    int idx = blockIdx.x * 256 + threadIdx.x;
    if (idx < 98304) {                                   // W12T[c*384+k]
        int c = idx / 384, k = idx - c * 384;
        float v = 0.f;
        if (c < 128) { if (k < 128) v = W_gat[k * 128 + c]; }
        else {
            int cc = c - 128;
            if (k >= 256)       v = W1r[(k - 256) * 128 + cc];
            else if (k >= 128)  v = W1l[(k - 128) * 128 + cc];
        }
        W12T[idx] = f2bf(v);
    } else if (idx < 229376) {                           // W2cT[c*512+k]
        int t = idx - 98304;
        int c = t >> 9, k = t & 511;
        float v = (k < 256) ? W2l[k * 256 + c] : W2r[(k - 256) * 256 + c];
        W2cT[t] = f2bf(v);
    } else if (idx < 229376 + 128) {
        int k = idx - 229376;
        float s = 0.f, d = 0.f;
        for (int c = 0; c < 128; ++c) {
            float w = W_gat[k * 128 + c];
            s += w * att_s[c]; d += w * att_d[c];
        }
        vs[k] = s; vd[k] = d;
    }
}

// ---------------- conv x -> bf16 (combo3[:,256:384]) + attention logits (wave per node) ----------------
__global__ __launch_bounds__(256) void conv_x_asad(
    const float* __restrict__ x, const float* __restrict__ vs, const float* __restrict__ vd,
    unsigned short* __restrict__ combo3, float* __restrict__ as_, float* __restrict__ ad_, int N)
{
    const int wave = threadIdx.x >> 6, lane = threadIdx.x & 63;
    const int i = blockIdx.x * 4 + wave;
    if (i >= N) return;
    float2 xv = *(const float2*)(x + (size_t)i * 128 + 2 * lane);
    float2 vsv = *(const float2*)(vs + 2 * lane);
    float2 vdv = *(const float2*)(vd + 2 * lane);
    float s = xv.x * vsv.x + xv.y * vsv.y;
    float d = xv.x * vdv.x + xv.y * vdv.y;
    #pragma unroll
    for (int off = 32; off > 0; off >>= 1) {
        s += __shfl_xor(s, off);
        d += __shfl_xor(d, off);
    }
    if (lane == 0) { as_[i] = s; ad_[i] = d; }
    unsigned pk = (unsigned)f2bf(xv.x) | ((unsigned)f2bf(xv.y) << 16);
    *(unsigned*)(combo3 + (size_t)i * 384 + 256 + 2 * lane) = pk;
}

// ---------------- CSR build via 2-level bucket sort (no global atomics) ----------------
__global__ __launch_bounds__(256) void radix_hist(
    const int* __restrict__ dst, int E, int* __restrict__ blockhist, int B)
{
    const int blk = blockIdx.x, t = threadIdx.x;
    __shared__ int hist[256];
    hist[t] = 0; __syncthreads();
    const int chunk = blk * CA, cend = min(chunk + CA, E);
    for (int j = chunk + t; j < cend; j += 256)
        atomicAdd(&hist[((unsigned)dst[j]) >> 8], 1);
    __syncthreads();
    blockhist[t * B + blk] = hist[t];       // bin-major layout
}

__global__ __launch_bounds__(256) void scan_rows(
    int* __restrict__ blockhist, int B, int* __restrict__ bintot)
{
    const int bin = blockIdx.x, t = threadIdx.x;
    __shared__ int tmp[256];
    __shared__ int carry;
    if (t == 0) carry = 0;
    __syncthreads();
    const int base = bin * B;
    for (int off0 = 0; off0 < B; off0 += 256) {
        int i = off0 + t;
        int v = (i < B) ? blockhist[base + i] : 0;
        tmp[t] = v; __syncthreads();
        for (int off = 1; off < 256; off <<= 1) {
            int a = (t >= off) ? tmp[t - off] : 0;
            __syncthreads();
            tmp[t] += a;
            __syncthreads();
        }
        int incl = tmp[t] + carry;
        if (i < B) blockhist[base + i] = incl - v;
        __syncthreads();
        if (t == 255) carry = incl;
        __syncthreads();
    }
    if (t == 0) bintot[bin] = carry;
}

__global__ __launch_bounds__(256) void scan_bins(
    const int* __restrict__ bintot, int* __restrict__ bucket_base, int E)
{
    const int t = threadIdx.x;
    __shared__ int tmp[256];
    int v = bintot[t];
    tmp[t] = v; __syncthreads();
    for (int off = 1; off < 256; off <<= 1) {
        int a = (t >= off) ? tmp[t - off] : 0;
        __syncthreads();
        tmp[t] += a;
        __syncthreads();
    }
    bucket_base[t] = tmp[t] - v;
    if (t == 255) bucket_base[256] = E;
}

__global__ __launch_bounds__(256) void radix_scatter(
    const int* __restrict__ src, const int* __restrict__ dst, int E,
    const int* __restrict__ rowscan, const int* __restrict__ bucket_base,
    int B, unsigned int* __restrict__ srt)
{
    const int blk = blockIdx.x, t = threadIdx.x;
    __shared__ int hist[256], lscan[256], lcur[256], gbase[256];
    __shared__ unsigned int recs[CA];
    hist[t] = 0; __syncthreads();
    const int chunk = blk * CA, cend = min(chunk + CA, E);
    for (int j = chunk + t; j < cend; j += 256)
        atomicAdd(&hist[((unsigned)dst[j]) >> 8], 1);
    __syncthreads();
    lscan[t] = hist[t]; __syncthreads();
    for (int off = 1; off < 256; off <<= 1) {
        int a = (t >= off) ? lscan[t - off] : 0;
        __syncthreads();
        lscan[t] += a;
        __syncthreads();
    }
    int excl = lscan[t] - hist[t];
    __syncthreads();
    lscan[t] = excl; lcur[t] = excl;
    gbase[t] = bucket_base[t] + rowscan[t * B + blk];
    __syncthreads();
    for (int j = chunk + t; j < cend; j += 256) {
        int d = dst[j];
        unsigned int r = ((unsigned)d << 16) | (unsigned)src[j];
        int p = atomicAdd(&lcur[((unsigned)d) >> 8], 1);
        recs[p] = r;
    }
    __syncthreads();
    const int cnt = cend - chunk;
    for (int k = t; k < cnt; k += 256) {
        unsigned int r = recs[k];
        int bin = r >> 24;
        srt[gbase[bin] + (k - lscan[bin])] = r;
    }
}

__global__ __launch_bounds__(256) void bucket_sort(
    const unsigned int* __restrict__ srt, const int* __restrict__ bucket_base,
    unsigned short* __restrict__ col_src, int* __restrict__ rp, int N, int E)
{
    const int b = blockIdx.x, t = threadIdx.x;
    const int beg = bucket_base[b], end = bucket_base[b + 1];
    const int cnt = end - beg;
    __shared__ int hist[256], lscan[256], lcur[256];
    __shared__ unsigned int recs[CAPB];
    __shared__ unsigned short outr[CAPB];
    hist[t] = 0; __syncthreads();
    const bool fits = cnt <= CAPB;
    if (fits) {
        for (int j = beg + t; j < end; j += 256) {
            unsigned int r = srt[j];
            recs[j - beg] = r;
            atomicAdd(&hist[(r >> 16) & 255], 1);
        }
    } else {
        for (int j = beg + t; j < end; j += 256)
            atomicAdd(&hist[(srt[j] >> 16) & 255], 1);
    }
    __syncthreads();
    lscan[t] = hist[t]; __syncthreads();
    for (int off = 1; off < 256; off <<= 1) {
        int a = (t >= off) ? lscan[t - off] : 0;
        __syncthreads();
        lscan[t] += a;
        __syncthreads();
    }
    int excl = lscan[t] - hist[t];
    __syncthreads();
    lscan[t] = excl; lcur[t] = excl;
    int d = (b << 8) + t;
    if (d < N) rp[d] = beg + excl;
    if (b == gridDim.x - 1 && t == 0) rp[N] = E;
    __syncthreads();
    if (fits) {
        for (int k = t; k < cnt; k += 256) {
            unsigned int r = recs[k];
            int p = atomicAdd(&lcur[(r >> 16) & 255], 1);
            outr[p] = (unsigned short)(r & 0xFFFFu);
        }
        __syncthreads();
        for (int k = t; k < cnt; k += 256)
            col_src[beg + k] = outr[k];
    } else {
        for (int j = beg + t; j < end; j += 256) {
            unsigned int r = srt[j];
            int p = atomicAdd(&lcur[(r >> 16) & 255], 1);
            col_src[beg + p] = (unsigned short)(r & 0xFFFFu);
        }
    }
}

// ---------------- fused GAT-weighted mean + SAGE1 mean over x (bf16 payload) ----------------
// 2 nodes per wave: lanes 0-31 = node A, 32-63 = node B; 2 groups of 16 per node.
__global__ __launch_bounds__(256) void gat_sage1(
    const int* __restrict__ row_ptr, const unsigned short* __restrict__ col_src,
    const float* __restrict__ as_, const float* __restrict__ ad_,
    unsigned short* __restrict__ combo3, int N)
{
    const int wave = threadIdx.x >> 6, lane = threadIdx.x & 63;
    const int half = lane >> 5, hl = lane & 31;
    const int g2 = (lane >> 4) & 1, l15 = lane & 15;
    const int h32 = half << 5;
    const int i = blockIdx.x * 8 + wave * 2 + half;
    const bool valid = i < N;

    const int beg = valid ? row_ptr[i] : 0;
    const int end = valid ? row_ptr[i + 1] : 0;
    const int deg = end - beg;
    const float adi = valid ? ad_[i] : 0.f;
    const float wself = valid ? __expf(lrelu(as_[i] + adi)) : 0.f;

    int j = beg + hl;
    int sn_l = (j < end) ? (int)col_src[j] : 0;
    float w_l = (j < end) ? __expf(lrelu(as_[sn_l] + adi)) : 0.f;
    int o_l = sn_l * 768;                      // pre-scaled row byte-offset

    const char* cb = (const char*)combo3;
    const unsigned lo = 512u + 16u * (unsigned)l15;   // x-part col slice within row

    uint4 sv = ld16(cb, (unsigned)(valid ? i : 0) * 768u + lo);
    const int dc = deg < 32 ? deg : 32;
    const int nr = dc >> 2;                    // full 4-edge rounds (2 per group)
    uint4 pv0, pv1; float pw0 = 0.f, pw1 = 0.f;
    if (nr > 0) {
        int so0 = __shfl(o_l, h32 + g2), so1 = __shfl(o_l, h32 + 2 + g2);
        pw0 = __shfl(w_l, h32 + g2); pw1 = __shfl(w_l, h32 + 2 + g2);
        pv0 = ld16(cb, lo + (unsigned)so0);
        pv1 = ld16(cb, lo + (unsigned)so1);
    }

    float2a aw2[4], ap2[4];
    {   // self term (weighted only; g2==0 carries it)
        float wm = (g2 == 0) ? wself : 0.f;
        float2a wm2; wm2[0] = wm; wm2[1] = wm;
        aw2[0] = wm2 * bf2(sv.x); aw2[1] = wm2 * bf2(sv.y);
        aw2[2] = wm2 * bf2(sv.z); aw2[3] = wm2 * bf2(sv.w);
        #pragma unroll
        for (int k = 0; k < 4; ++k) { ap2[k][0] = 0.f; ap2[k][1] = 0.f; }
    }

    for (int r = 0; r < nr; ++r) {             // prefetched 4-edge rounds
        uint4 cv0 = pv0, cv1 = pv1;
        float cw0 = pw0, cw1 = pw1;
        if (r + 1 < nr) {
            int b4 = (r + 1) * 4;
            int so0 = __shfl(o_l, h32 + b4 + g2), so1 = __shfl(o_l, h32 + b4 + 2 + g2);
            pw0 = __shfl(w_l, h32 + b4 + g2); pw1 = __shfl(w_l, h32 + b4 + 2 + g2);
            pv0 = ld16(cb, lo + (unsigned)so0);
            pv1 = ld16(cb, lo + (unsigned)so1);
        }
        accb(aw2, ap2, cw0, cv0);
        accb(aw2, ap2, cw1, cv1);
    }
    for (int j2 = nr * 4; j2 < dc; j2 += 2) {  // masked pair tail
        int eidx = j2 + g2;
        bool val = eidx < dc;
        int so  = __shfl(o_l, h32 + (val ? eidx : 0));
        float w = __shfl(w_l, h32 + (val ? eidx : 0));
        uint4 v = ld16(cb, lo + (unsigned)so);
        accbm(aw2, ap2, val ? w : 0.f, val ? 1.f : 0.f, v);
    }
    for (int j3 = 32; j3 < deg; ++j3) {        // rare tail (deg > 32), gather part
        int sn = col_src[beg + j3];
        float w = __expf(lrelu(as_[sn] + adi));
        uint4 v = ld16(cb, lo + (unsigned)(sn * 768));
        accbm(aw2, ap2, (g2 == 0) ? w : 0.f, (g2 == 0) ? 1.f : 0.f, v);
    }

    // denominator: per-lane partial (32 edges/half) + rare tail, then 5-level half-reduce
    float s = w_l;
    for (int jj = beg + hl + 32; jj < end; jj += 32)
        s += __expf(lrelu(as_[col_src[jj]] + adi));
    #pragma unroll
    for (int off = 16; off > 0; off >>= 1) s += __shfl_xor(s, off);
    const float denom = s + wself;

    float aw[8], ap[8];
    #pragma unroll
    for (int k = 0; k < 4; ++k) {
        aw[2 * k] = aw2[k][0]; aw[2 * k + 1] = aw2[k][1];
        ap[2 * k] = ap2[k][0]; ap[2 * k + 1] = ap2[k][1];
    }
    #pragma unroll
    for (int k = 0; k < 8; ++k) {              // single cross-group combine (within half)
        aw[k] += __shfl_xor(aw[k], 16);
        ap[k] += __shfl_xor(ap[k], 16);
    }
    if (valid && g2 == 0) {     // wx -> combo3[:,0:128]
        float inv = 1.f / denom;
        uint4 pk;
        pk.x = (unsigned)f2bf(aw[0] * inv) | ((unsigned)f2bf(aw[1] * inv) << 16);
        pk.y = (unsigned)f2bf(aw[2] * inv) | ((unsigned)f2bf(aw[3] * inv) << 16);
        pk.z = (unsigned)f2bf(aw[4] * inv) | ((unsigned)f2bf(aw[5] * inv) << 16);
        pk.w = (unsigned)f2bf(aw[6] * inv) | ((unsigned)f2bf(aw[7] * inv) << 16);
        *(uint4*)(combo3 + (size_t)i * 384 + 8 * l15) = pk;
    } else if (valid && g2 == 1) {  // agg1 -> combo3[:,128:256]
        float dinv = 1.f / fmaxf((float)deg, 1.f);
        uint4 pk;
        pk.x = (unsigned)f2bf(ap[0] * dinv) | ((unsigned)f2bf(ap[1] * dinv) << 16);
        pk.y = (unsigned)f2bf(ap[2] * dinv) | ((unsigned)f2bf(ap[3] * dinv) << 16);
        pk.z = (unsigned)f2bf(ap[4] * dinv) | ((unsigned)f2bf(ap[5] * dinv) << 16);
        pk.w = (unsigned)f2bf(ap[6] * dinv) | ((unsigned)f2bf(ap[7] * dinv) << 16);
        *(uint4*)(combo3 + (size_t)i * 384 + 128 + 8 * l15) = pk;
    }
}

// swizzled staging column for lane slot v: global kk block to fetch
__device__ __forceinline__ int swz_kk(int v) {
    return (((v & 7) ^ ((v >> 3) & 7)) * 8);
}

// ---------------- GEMM h = combo3 @ W12T^T + bias, fused LN1+ReLU -> bf16 h + fp8 hq ----------------
// BM=64, BN=256, BK=64, K=384. XOR-swizzled LDS. K-split by wave (skips W12T zero block).
__global__ __launch_bounds__(256) void gemm12_ln(
    const unsigned short* __restrict__ combo3, int M,
    const unsigned short* __restrict__ W12T,
    const float* __restrict__ b_gat, const float* __restrict__ b1l,
    const float* __restrict__ g1, const float* __restrict__ bb1,
    unsigned short* __restrict__ combo2, unsigned char* __restrict__ hq)
{
    __shared__ __align__(16) unsigned short As[64 * 64];
    __shared__ __align__(16) unsigned short Ws[256 * 64];   // staging uses first 128x64; Hs repack uses all
    const int tid = threadIdx.x;
    const int bm = blockIdx.x * 64;
    const int wave = tid >> 6, lane = tid & 63;
    const int quad = lane >> 4, l15 = lane & 15;
    const int swz_rd = (l15 & 7) * 8;          // read-side XOR

    float4a acc[4][4];
    const float4a z4 = {0.f, 0.f, 0.f, 0.f};
    #pragma unroll
    for (int i = 0; i < 4; ++i)
        #pragma unroll
        for (int j = 0; j < 4; ++j) acc[i][j] = z4;

    for (int k0 = 0; k0 < 384; k0 += 64) {
        const bool low = k0 < 128;
        const int rbase = low ? 0 : 128;       // active output-col half for this K-step
        #pragma unroll
        for (int it = 0; it < 2; ++it) {
            int v = tid + it * 256;
            int r = v >> 3, kk = swz_kk(v);
            if (bm + r < M)
                load_lds16(combo3 + (size_t)(bm + r) * 384 + k0 + kk, &As[v * 8]);
        }
        #pragma unroll
        for (int it = 0; it < 4; ++it) {       // stage only the active 128-row half of W12T
            int v = tid + it * 256;            // 0..1023: rloc 0..127
            int r = v >> 3, kk = swz_kk(v);
            load_lds16(W12T + (size_t)(rbase + r) * 384 + k0 + kk, &Ws[v * 8]);
        }
        __syncthreads();
        if ((wave < 2) == low) {               // wave active only in its K-range
            #pragma unroll
            for (int ks = 0; ks < 64; ks += 32) {
                short8 af[4], bfr[4];
                #pragma unroll
                for (int i = 0; i < 4; ++i)
                    af[i] = *(const short8*)(&As[(i * 16 + l15) * 64 + ((ks + quad * 8) ^ swz_rd)]);
                #pragma unroll
                for (int j = 0; j < 4; ++j)
                    bfr[j] = *(const short8*)(&Ws[((wave & 1) * 64 + j * 16 + l15) * 64 + ((ks + quad * 8) ^ swz_rd)]);
                #pragma unroll
                for (int i = 0; i < 4; ++i)
                    #pragma unroll
                    for (int j = 0; j < 4; ++j)
                        acc[i][j] = __builtin_amdgcn_mfma_f32_16x16x32_bf16(af[i], bfr[j], acc[i][j], 0, 0, 0);
            }
        }
        __syncthreads();
    }
    // epilogue: bias + LN + ReLU
    int col[4]; float bcol[4], gc[4], bc2[4];
    #pragma unroll
    for (int j = 0; j < 4; ++j) {
        int c = wave * 64 + j * 16 + l15;
        col[j] = c;
        bcol[j] = (c < 128) ? b_gat[c] : b1l[c - 128];
        gc[j] = g1[c]; bc2[j] = bb1[c];
    }
    float* lsum = (float*)As;         // 256 floats
    float* lsq  = lsum + 256;         // 256 floats
    #pragma unroll
    for (int i = 0; i < 4; ++i)
        #pragma unroll
        for (int r = 0; r < 4; ++r) {
            float ps = 0.f, pq = 0.f;
            #pragma unroll
            for (int j = 0; j < 4; ++j) {
                float v = acc[i][j][r] + bcol[j];
                ps += v; pq += v * v;
            }
            #pragma unroll
            for (int off = 1; off < 16; off <<= 1) {
                ps += __shfl_xor(ps, off);
                pq += __shfl_xor(pq, off);
            }
            if (l15 == 0) {
                int row = i * 16 + quad * 4 + r;
                lsum[row * 4 + wave] = ps;
                lsq[row * 4 + wave]  = pq;
            }
        }
    __syncthreads();
    unsigned short* Hs = Ws;          // 64 x 256 bf16 repack buffer
    #pragma unroll
    for (int i = 0; i < 4; ++i)
        #pragma unroll
        for (int r = 0; r < 4; ++r) {
            int row = i * 16 + quad * 4 + r;
            float su = lsum[row * 4] + lsum[row * 4 + 1] + lsum[row * 4 + 2] + lsum[row * 4 + 3];
            float sq = lsq[row * 4] + lsq[row * 4 + 1] + lsq[row * 4 + 2] + lsq[row * 4 + 3];
            float mu = su * (1.f / 256.f);
            float var = sq * (1.f / 256.f) - mu * mu;
            float rs = rsqrtf(var + LN_EPS);
            #pragma unroll
            for (int j = 0; j < 4; ++j) {
                float v = acc[i][j][r] + bcol[j];
                float o = fmaxf((v - mu) * rs * gc[j] + bc2[j], 0.f);
                Hs[row * 256 + col[j]] = f2bf(o);
            }
        }
    __syncthreads();
    #pragma unroll
    for (int it = 0; it < 8; ++it) {        // bf16 h -> combo2[:,256:512]
        int v = tid + it * 256;
        int r = v >> 5, cc = (v & 31) * 8;
        if (bm + r < M)
            *(uint4*)(combo2 + (size_t)(bm + r) * 512 + 256 + cc) = *(const uint4*)(&Hs[r * 256 + cc]);
    }
    #pragma unroll
    for (int it = 0; it < 4; ++it) {        // fp8 h -> hq (gather payload)
        int v = tid + it * 256;
        int r = v >> 4, c16 = (v & 15) * 16;
        if (bm + r < M) {
            uint4 o;
            #pragma unroll
            for (int q = 0; q < 4; ++q) {
                unsigned int w0 = *(const unsigned int*)(&Hs[r * 256 + c16 + q * 4 + 0]);
                unsigned int w1 = *(const unsigned int*)(&Hs[r * 256 + c16 + q * 4 + 2]);
                unsigned int t0 = __builtin_amdgcn_cvt_pk_fp8_f32(bflo(w0), bfhi(w0), 0, false);
                unsigned int t1 = __builtin_amdgcn_cvt_pk_fp8_f32(bflo(w1), bfhi(w1), t0, true);
                ((unsigned int*)&o)[q] = t1;
            }
            *(uint4*)(hq + (size_t)(bm + r) * 256 + c16) = o;
        }
    }
}

// ---------------- SAGE2 mean aggregate over fp8 hq (2 nodes per wave, half-split) ----------------
__global__ __launch_bounds__(256) void sage2_agg(
    const int* __restrict__ row_ptr, const unsigned short* __restrict__ col_src,
    const unsigned char* __restrict__ hq, unsigned short* __restrict__ combo2, int N)
{
    const int wave = threadIdx.x >> 6, lane = threadIdx.x & 63;
    const int half = lane >> 5, hl = lane & 31;
    const int g2 = (lane >> 4) & 1, l15 = lane & 15;
    const int h32 = half << 5;
    const int i = blockIdx.x * 8 + wave * 2 + half;
    const bool valid = i < N;

    const int beg = valid ? row_ptr[i] : 0;
    const int end = valid ? row_ptr[i + 1] : 0;
    const int deg = end - beg;
    int cidx = (beg + hl < end) ? (int)col_src[beg + hl] : 0;
    int o_l = cidx * 256;                      // pre-scaled row byte-offset
    const char* hb = (const char*)hq;
    const unsigned lo = 16u * (unsigned)l15;
    float2a a2[8];
    #pragma unroll
    for (int k = 0; k < 8; ++k) { a2[k][0] = 0.f; a2[k][1] = 0.f; }
    const int dc = deg < 32 ? deg : 32;
    int j = 0;
    for (; j + 4 <= dc; j += 4) {          // unmasked 4-edge rounds (2 per group)
        #pragma unroll
        for (int u = 0; u < 2; ++u) {
            int eidx = j + 2 * u + g2;
            int so = __shfl(o_l, h32 + eidx);
            uint4 v = ld16(hb, lo + (unsigned)so);
            a2[0] += __builtin_amdgcn_cvt_pk_f32_fp8(v.x, false);
            a2[1] += __builtin_amdgcn_cvt_pk_f32_fp8(v.x, true);
            a2[2] += __builtin_amdgcn_cvt_pk_f32_fp8(v.y, false);
            a2[3] += __builtin_amdgcn_cvt_pk_f32_fp8(v.y, true);
            a2[4] += __builtin_amdgcn_cvt_pk_f32_fp8(v.z, false);
            a2[5] += __builtin_amdgcn_cvt_pk_f32_fp8(v.z, true);
            a2[6] += __builtin_amdgcn_cvt_pk_f32_fp8(v.w, false);
            a2[7] += __builtin_amdgcn_cvt_pk_f32_fp8(v.w, true);
        }
    }
    for (; j < dc; j += 2) {               // masked pair tail
        int eidx = j + g2;
        bool val = eidx < dc;
        int so = __shfl(o_l, h32 + (val ? eidx : 0));
        uint4 v = ld16(hb, lo + (unsigned)so);
        float mlt = val ? 1.f : 0.f;
        float2a m2; m2[0] = mlt; m2[1] = mlt;
        a2[0] += m2 * __builtin_amdgcn_cvt_pk_f32_fp8(v.x, false);
        a2[1] += m2 * __builtin_amdgcn_cvt_pk_f32_fp8(v.x, true);
        a2[2] += m2 * __builtin_amdgcn_cvt_pk_f32_fp8(v.y, false);
        a2[3] += m2 * __builtin_amdgcn_cvt_pk_f32_fp8(v.y, true);
        a2[4] += m2 * __builtin_amdgcn_cvt_pk_f32_fp8(v.z, false);
        a2[5] += m2 * __builtin_amdgcn_cvt_pk_f32_fp8(v.z, true);
        a2[6] += m2 * __builtin_amdgcn_cvt_pk_f32_fp8(v.w, false);
        a2[7] += m2 * __builtin_amdgcn_cvt_pk_f32_fp8(v.w, true);
    }
    for (int j3 = 32; j3 < deg; ++j3) {    // rare tail (deg > 32)
        int sn = col_src[beg + j3];
        uint4 v = ld16(hb, lo + (unsigned)(sn * 256));
        float mlt = (g2 == 0) ? 1.f : 0.f;
        float2a m2; m2[0] = mlt; m2[1] = mlt;
        a2[0] += m2 * __builtin_amdgcn_cvt_pk_f32_fp8(v.x, false);
        a2[1] += m2 * __builtin_amdgcn_cvt_pk_f32_fp8(v.x, true);
        a2[2] += m2 * __builtin_amdgcn_cvt_pk_f32_fp8(v.y, false);
        a2[3] += m2 * __builtin_amdgcn_cvt_pk_f32_fp8(v.y, true);
        a2[4] += m2 * __builtin_amdgcn_cvt_pk_f32_fp8(v.z, false);
        a2[5] += m2 * __builtin_amdgcn_cvt_pk_f32_fp8(v.z, true);
        a2[6] += m2 * __builtin_amdgcn_cvt_pk_f32_fp8(v.w, false);
        a2[7] += m2 * __builtin_amdgcn_cvt_pk_f32_fp8(v.w, true);
    }
    float a[16];
    #pragma unroll
    for (int k = 0; k < 8; ++k) { a[2 * k] = a2[k][0]; a[2 * k + 1] = a2[k][1]; }
    #pragma unroll
    for (int k = 0; k < 16; ++k)               // single cross-group combine (within half)
        a[k] += __shfl_xor(a[k], 16);
    if (valid && g2 == 0) {
        float dinv = 1.f / fmaxf((float)deg, 1.f);
        uint4 pk0, pk1;
        pk0.x = (unsigned)f2bf(a[0] * dinv)  | ((unsigned)f2bf(a[1] * dinv)  << 16);
        pk0.y = (unsigned)f2bf(a[2] * dinv)  | ((unsigned)f2bf(a[3] * dinv)  << 16);
        pk0.z = (unsigned)f2bf(a[4] * dinv)  | ((unsigned)f2bf(a[5] * dinv)  << 16);
        pk0.w = (unsigned)f2bf(a[6] * dinv)  | ((unsigned)f2bf(a[7] * dinv)  << 16);
        pk1.x = (unsigned)f2bf(a[8] * dinv)  | ((unsigned)f2bf(a[9] * dinv)  << 16);
        pk1.y = (unsigned)f2bf(a[10] * dinv) | ((unsigned)f2bf(a[11] * dinv) << 16);
        pk1.z = (unsigned)f2bf(a[12] * dinv) | ((unsigned)f2bf(a[13] * dinv) << 16);
        pk1.w = (unsigned)f2bf(a[14] * dinv) | ((unsigned)f2bf(a[15] * dinv) << 16);
        *(uint4*)(combo2 + (size_t)i * 512 + 16 * l15)     = pk0;
        *(uint4*)(combo2 + (size_t)i * 512 + 16 * l15 + 8) = pk1;
    }
}

// ---------------- GEMM h2 = combo2 @ W2cT^T + b2l, fused LN2+ReLU+classifier -> out ----------------
__global__ __launch_bounds__(256) void gemm3_out(
    const unsigned short* __restrict__ combo2, int M,
    const unsigned short* __restrict__ W2cT,
    const float* __restrict__ b2l,
    const float* __restrict__ g2, const float* __restrict__ bb2,
    const float* __restrict__ Wc, const float* __restrict__ bc,
    float* __restrict__ out)
{
    __shared__ __align__(16) unsigned short As[64 * 64];
    __shared__ __align__(16) unsigned short Ws[256 * 64];
    const int tid = threadIdx.x;
    const int bm = blockIdx.x * 64;
    const int wave = tid >> 6, lane = tid & 63;
    const int quad = lane >> 4, l15 = lane & 15;
    const int swz_rd = (l15 & 7) * 8;

    float4a acc[4][4];
    const float4a z4 = {0.f, 0.f, 0.f, 0.f};
    #pragma unroll
    for (int i = 0; i < 4; ++i)
        #pragma unroll
        for (int j = 0; j < 4; ++j) acc[i][j] = z4;

    for (int k0 = 0; k0 < 512; k0 += 64) {
        #pragma unroll
        for (int it = 0; it < 2; ++it) {
            int v = tid + it * 256;
            int r = v >> 3, kk = swz_kk(v);
            if (bm + r < M)
                load_lds16(combo2 + (size_t)(bm + r) * 512 + k0 + kk, &As[v * 8]);
        }
        #pragma unroll
        for (int it = 0; it < 8; ++it) {
            int v = tid + it * 256;
            int r = v >> 3, kk = swz_kk(v);
            load_lds16(W2cT + (size_t)r * 512 + k0 + kk, &Ws[v * 8]);
        }
        __syncthreads();
        #pragma unroll
        for (int ks = 0; ks < 64; ks += 32) {
            short8 af[4], bfr[4];
            #pragma unroll
            for (int i = 0; i < 4; ++i)
                af[i] = *(const short8*)(&As[(i * 16 + l15) * 64 + ((ks + quad * 8) ^ swz_rd)]);
            #pragma unroll
            for (int j = 0; j < 4; ++j)
                bfr[j] = *(const short8*)(&Ws[(wave * 64 + j * 16 + l15) * 64 + ((ks + quad * 8) ^ swz_rd)]);
            #pragma unroll
            for (int i = 0; i < 4; ++i)
                #pragma unroll
                for (int j = 0; j < 4; ++j)
                    acc[i][j] = __builtin_amdgcn_mfma_f32_16x16x32_bf16(af[i], bfr[j], acc[i][j], 0, 0, 0);
        }
        __syncthreads();
    }
    int col[4]; float bcol[4], gc[4], bc2[4], wcl[4];
    #pragma unroll
    for (int j = 0; j < 4; ++j) {
        int c = wave * 64 + j * 16 + l15;
        col[j] = c;
        bcol[j] = b2l[c];
        gc[j] = g2[c]; bc2[j] = bb2[c]; wcl[j] = Wc[c];
    }
    float* lsum = (float*)As;
    float* lsq  = lsum + 256;
    float* ldot = lsum + 512;
    #pragma unroll
    for (int i = 0; i < 4; ++i)
        #pragma unroll
        for (int r = 0; r < 4; ++r) {
            float ps = 0.f, pq = 0.f;
            #pragma unroll
            for (int j = 0; j < 4; ++j) {
                float v = acc[i][j][r] + bcol[j];
                ps += v; pq += v * v;
            }
            #pragma unroll
            for (int off = 1; off < 16; off <<= 1) {
                ps += __shfl_xor(ps, off);
                pq += __shfl_xor(pq, off);
            }
            if (l15 == 0) {
                int row = i * 16 + quad * 4 + r;
                lsum[row * 4 + wave] = ps;
                lsq[row * 4 + wave]  = pq;
            }
        }
    __syncthreads();
    #pragma unroll
    for (int i = 0; i < 4; ++i)
        #pragma unroll
        for (int r = 0; r < 4; ++r) {
            int row = i * 16 + quad * 4 + r;
            float su = lsum[row * 4] + lsum[row * 4 + 1] + lsum[row * 4 + 2] + lsum[row * 4 + 3];
            float sq = lsq[row * 4] + lsq[row * 4 + 1] + lsq[row * 4 + 2] + lsq[row * 4 + 3];
            float mu = su * (1.f / 256.f);
            float var = sq * (1.f / 256.f) - mu * mu;
            float rs = rsqrtf(var + LN_EPS);
            float pd = 0.f;
            #pragma unroll
            for (int j = 0; j < 4; ++j) {
                float v = acc[i][j][r] + bcol[j];
                float o = fmaxf((v - mu) * rs * gc[j] + bc2[j], 0.f);
                pd += o * wcl[j];
            }
            #pragma unroll
            for (int off = 1; off < 16; off <<= 1) pd += __shfl_xor(pd, off);
            if (l15 == 0) ldot[row * 4 + wave] = pd;
        }
    __syncthreads();
    if (tid < 64 && bm + tid < M)
        out[bm + tid] = ldot[tid * 4] + ldot[tid * 4 + 1] + ldot[tid * 4 + 2] + ldot[tid * 4 + 3] + bc[0];
}

extern "C" void kernel_launch(void* const* d_in, const int* in_sizes, int n_in,
                              void* d_out, int out_size, void* d_ws, size_t ws_size,
                              hipStream_t stream)
{
    const float* x     = (const float*)d_in[0];
    const int*   ei    = (const int*)d_in[1];
    const float* W_gat = (const float*)d_in[2];
    const float* att_s = (const float*)d_in[3];
    const float* att_d = (const float*)d_in[4];
    const float* b_gat = (const float*)d_in[5];
    const float* W1l   = (const float*)d_in[6];
    const float* b1l   = (const float*)d_in[7];
    const float* W1r   = (const float*)d_in[8];
    const float* ln1g  = (const float*)d_in[9];
    const float* ln1b  = (const float*)d_in[10];
    const float* W2l   = (const float*)d_in[11];
    const float* b2l   = (const float*)d_in[12];
    const float* W2r   = (const float*)d_in[13];
    const float* ln2g  = (const float*)d_in[14];
    const float* ln2b  = (const float*)d_in[15];
    const float* Wc    = (const float*)d_in[16];
    const float* bc    = (const float*)d_in[17];

    const int N = in_sizes[0] / 128;
    const int E = in_sizes[1] / 2;
    const int* srcp = ei;
    const int* dstp = ei + E;

    char* p = (char*)d_ws;
    unsigned short* combo3 = (unsigned short*)p; p += (size_t)N * 384 * 2;  // [wx | agg1 | x_bf]
    unsigned short* combo2 = (unsigned short*)p; p += (size_t)N * 512 * 2;  // [agg2 | h_ln]
    unsigned char* hq     = (unsigned char*)p;  p += (size_t)N * 256;       // fp8 h (gather payload)
    float* as_    = (float*)p;                 p += (size_t)N * 4;
    float* ad_    = (float*)p;                 p += (size_t)N * 4;
    float* vs     = (float*)p;                 p += 128 * 4;
    float* vd     = (float*)p;                 p += 128 * 4;
    unsigned short* W12T = (unsigned short*)p; p += (size_t)256 * 384 * 2;
    unsigned short* W2cT = (unsigned short*)p; p += (size_t)256 * 512 * 2;
    unsigned int* srt    = (unsigned int*)p;   p += (size_t)E * 4;
    unsigned short* col_src = (unsigned short*)p; p += (((size_t)E * 2 + 15) & ~15ull);
    int* rp       = (int*)p;                   p += (size_t)(N + 1) * 4;
    const int B   = (E + CA - 1) / CA;         // radix blocks
    int* blockhist = (int*)p;                  p += (size_t)256 * B * 4;
    int* bucket_base = (int*)p;                p += 257 * 4;
    int* bintot   = (int*)p;                   p += 256 * 4;

    dim3 b256(256);
    const int mb64 = (N + 63) / 64;
    const int nb = (N + 255) >> 8;             // coarse buckets
    const int prep_total = 229376 + 128;

    // --- prep + x conversion/logits ---
    hipLaunchKernelGGL(prep, dim3((prep_total + 255) / 256), b256, 0, stream,
                       W_gat, W1l, W1r, W2l, W2r, att_s, att_d, W12T, W2cT, vs, vd);
    hipLaunchKernelGGL(conv_x_asad, dim3((N + 3) / 4), b256, 0, stream,
                       x, vs, vd, combo3, as_, ad_, N);

    // --- CSR by dst: bucket sort (no global atomics; 2-level parallel scan) ---
    hipLaunchKernelGGL(radix_hist, dim3(B), b256, 0, stream, dstp, E, blockhist, B);
    hipLaunchKernelGGL(scan_rows, dim3(256), b256, 0, stream, blockhist, B, bintot);
    hipLaunchKernelGGL(scan_bins, dim3(1), b256, 0, stream, bintot, bucket_base, E);
    hipLaunchKernelGGL(radix_scatter, dim3(B), b256, 0, stream,
                       srcp, dstp, E, blockhist, bucket_base, B, srt);
    hipLaunchKernelGGL(bucket_sort, dim3(nb), b256, 0, stream,
                       srt, bucket_base, col_src, rp, N, E);

    // --- GAT wmean + SAGE1 mean over x (2 nodes/wave half-split) ---
    hipLaunchKernelGGL(gat_sage1, dim3((N + 7) / 8), b256, 0, stream,
                       rp, col_src, as_, ad_, combo3, N);

    // --- h = combo3 @ W12T^T + bias, LN1+ReLU fused -> combo2[:,256:512] bf16 + hq fp8 ---
    hipLaunchKernelGGL(gemm12_ln, dim3(mb64), b256, 0, stream,
                       combo3, N, W12T, b_gat, b1l, ln1g, ln1b, combo2, hq);

    // --- SAGE2 aggregate (fp8 gather, 2 nodes/wave half-split) -> combo2[:,0:256] ---
    hipLaunchKernelGGL(sage2_agg, dim3((N + 7) / 8), b256, 0, stream,
                       rp, col_src, hq, combo2, N);

    // --- h2 GEMM (BM=64, 4 waves) + LN2 + ReLU + classifier -> out ---
    hipLaunchKernelGGL(gemm3_out, dim3(mb64), b256, 0, stream,
                       combo2, N, W2cT, b2l, ln2g, ln2b, Wc, bc, (float*)d_out);
}